// Round 3
// baseline (256.137 us; speedup 1.0000x reference)
//
#include <hip/hip_runtime.h>
#include <math.h>

// Problem constants
#define NH 8
#define DDIM 64
#define NN 2
#define QQ 128
#define PPDIM 128
#define BBD 4
#define ROWS 512           // Q*B == P*B
#define EPSN 1e-5f
#define TEMPER 30.0f

// Workspace layout (float offsets)
#define WQ_R 0u            // [H][N][512][64] rows = q*4+b
#define WQ_I 524288u
#define WK_R 1048576u      // rows = p*4+b
#define WK_I 1572864u
#define VV_  2105344u      // 4 x [H][N][512][64]  (v1,v2,v3,v4)
#define C_R_ 4202496u      // [H][N][512]
#define C_I_ 4210688u
#define ACM_ 4218880u      // [H][N][Q][B][P]  magnitude only
#define AFF_ 6316032u      // (dead this version; PART aliases here)
#define PART_ AFF_

#define DOT4(acc, s, v)  { acc = fmaf((s).x,(v).x,acc); acc = fmaf((s).y,(v).y,acc); acc = fmaf((s).z,(v).z,acc); acc = fmaf((s).w,(v).w,acc); }
#define NDOT4(acc, s, v) { acc = fmaf(-(s).x,(v).x,acc); acc = fmaf(-(s).y,(v).y,acc); acc = fmaf(-(s).z,(v).z,acc); acc = fmaf(-(s).w,(v).w,acc); }

// ---------------------------------------------------------------------------
// K1: complex projection (pre-norm) + fused InstanceNorm partial stats.
// grid (16 rowtiles, 16 hn, 2 qk), block 512 (2 blocks/CU -> 16 waves/CU).
// Each thread: 4 outputs (dq = t>>5 in 0..15).
// ---------------------------------------------------------------------------
__global__ __launch_bounds__(512, 2) void k_proj(
    const float* __restrict__ qR, const float* __restrict__ qI,
    const float* __restrict__ kR, const float* __restrict__ kI,
    const float* __restrict__ WQr, const float* __restrict__ WQi,
    const float* __restrict__ WKr, const float* __restrict__ WKi,
    float* __restrict__ ws, float* __restrict__ part)
{
    __shared__ __align__(16) float sWT[2][64 * 64];     // transposed: [e][d]
    const int t  = threadIdx.x;
    const int rt = blockIdx.x;
    const int hn = blockIdx.y;
    const int z  = blockIdx.z;
    const int h = hn >> 1, n = hn & 1;
    const float* inR = z ? kR : qR;
    const float* inI = z ? kI : qI;
    const float* wr0 = (z ? WKr : WQr) + h * 4096;
    const float* wi0 = (z ? WKi : WQi) + h * 4096;
    float* outR = ws + (z ? WK_R : WQ_R);
    float* outI = ws + (z ? WK_I : WQ_I);
#pragma unroll
    for (int j = 0; j < 8; ++j) {
        int flat = t + 512 * j;
        int d = flat & 63, e = flat >> 6;
        sWT[0][e * 64 + d] = wr0[d * 64 + e];
        sWT[1][e * 64 + d] = wi0[d * 64 + e];
    }
    __syncthreads();
    const int row = t & 31, dq = t >> 5;     // dq 0..15, 4 outputs/thread
    const int rowg = rt * 32 + row;
    const float4* xr4 = (const float4*)(inR + (n * ROWS + rowg) * 64);
    const float4* xi4 = (const float4*)(inI + (n * ROWS + rowg) * 64);
    float ar[4], ai[4];
#pragma unroll
    for (int j = 0; j < 4; ++j) { ar[j] = 0.f; ai[j] = 0.f; }
    for (int ec = 0; ec < 16; ++ec) {
        float4 xrv = xr4[ec], xiv = xi4[ec];
        float xrs[4] = {xrv.x, xrv.y, xrv.z, xrv.w};
        float xis[4] = {xiv.x, xiv.y, xiv.z, xiv.w};
#pragma unroll
        for (int u = 0; u < 4; ++u) {
            int e = ec * 4 + u;
            float4 wr = *(const float4*)&sWT[0][e * 64 + dq * 4];
            float4 wi = *(const float4*)&sWT[1][e * 64 + dq * 4];
            float xr = xrs[u], xi = xis[u];
            ar[0] = fmaf(xr, wr.x, fmaf(-xi, wi.x, ar[0]));
            ar[1] = fmaf(xr, wr.y, fmaf(-xi, wi.y, ar[1]));
            ar[2] = fmaf(xr, wr.z, fmaf(-xi, wi.z, ar[2]));
            ar[3] = fmaf(xr, wr.w, fmaf(-xi, wi.w, ar[3]));
            ai[0] = fmaf(xr, wi.x, fmaf( xi, wr.x, ai[0]));
            ai[1] = fmaf(xr, wi.y, fmaf( xi, wr.y, ai[1]));
            ai[2] = fmaf(xr, wi.z, fmaf( xi, wr.z, ai[2]));
            ai[3] = fmaf(xr, wi.w, fmaf( xi, wr.w, ai[3]));
        }
    }
    float* oR = outR + ((unsigned)hn * ROWS + rowg) * 64 + dq * 4;
    float* oI = outI + ((unsigned)hn * ROWS + rowg) * 64 + dq * 4;
    *(float4*)oR = make_float4(ar[0], ar[1], ar[2], ar[3]);
    *(float4*)oI = make_float4(ai[0], ai[1], ai[2], ai[3]);
    // ---- fused stats partials: sum over this block's 32 rows ----
    float s_r[4], q_r8[4], s_i[4], q_i8[4];
#pragma unroll
    for (int i = 0; i < 4; ++i) {
        s_r[i] = ar[i]; q_r8[i] = ar[i] * ar[i];
        s_i[i] = ai[i]; q_i8[i] = ai[i] * ai[i];
    }
#pragma unroll
    for (int m = 1; m <= 16; m <<= 1) {
#pragma unroll
        for (int i = 0; i < 4; ++i) {
            s_r[i]  += __shfl_xor(s_r[i],  m);
            q_r8[i] += __shfl_xor(q_r8[i], m);
            s_i[i]  += __shfl_xor(s_i[i],  m);
            q_i8[i] += __shfl_xor(q_i8[i], m);
        }
    }
    if ((t & 31) == 0) {
        const int gr = (z * 2) * 16 + hn;        // out_r tensor group
        const int gi = (z * 2 + 1) * 16 + hn;    // out_i tensor group
#pragma unroll
        for (int i = 0; i < 4; ++i) {
            int d = dq * 4 + i;
            part[(unsigned)gr * 2048u + rt * 64 + d]          = s_r[i];
            part[(unsigned)gr * 2048u + 1024 + rt * 64 + d]   = q_r8[i];
            part[(unsigned)gi * 2048u + rt * 64 + d]          = s_i[i];
            part[(unsigned)gi * 2048u + 1024 + rt * 64 + d]   = q_i8[i];
        }
    }
}

// ---------------------------------------------------------------------------
// K2 (fused): role A = v-vectors + bias dots (blocks 0..511)
//             role B = AC magnitude scores (blocks 512..1535)
// ---------------------------------------------------------------------------
__global__ __launch_bounds__(256) void k_mid(
    const float* __restrict__ wqr, const float* __restrict__ wqi,
    const float* __restrict__ wkr, const float* __restrict__ wki,
    const float* __restrict__ part,
    const float* __restrict__ Ar,  const float* __restrict__ Ai,
    const float* __restrict__ Abr, const float* __restrict__ Abi,
    const float* __restrict__ grv, const float* __restrict__ btrv,
    const float* __restrict__ giv, const float* __restrict__ btiv,
    const float* __restrict__ gwr, const float* __restrict__ btwr,
    const float* __restrict__ gwi, const float* __restrict__ btwi,
    float* __restrict__ Vout, float* __restrict__ cR, float* __restrict__ cI,
    float* __restrict__ ACm)
{
    __shared__ __align__(16) float smem[11392];
    const int t = threadIdx.x;
    if (blockIdx.x < 512) {
        // =========================== role A: vvec ===========================
        float* sW0 = smem;            // [64][32]
        float* sW1 = smem + 2048;
        float* sX0 = smem + 4096;     // [64][32] swizzled
        float* sX1 = smem + 6144;
        float* sMu = smem + 8192;     // [2][64]
        float* sRs = smem + 8320;     // [2][64]
        const int b1 = blockIdx.x;
        const int rt = b1 & 15, eh = (b1 >> 4) & 1, hn = b1 >> 5, h = hn >> 1;
        if (t < 128) {
            int g = t >> 6, d = t & 63;
            int grp = (g ? 16 : 0) + hn;
            const float* ps = part + (unsigned)grp * 2048u + d;
            float s = 0.f, qq = 0.f;
#pragma unroll
            for (int r2 = 0; r2 < 16; ++r2) {
                s  += ps[r2 * 64];
                qq += ps[1024 + r2 * 64];
            }
            float m = s * (1.f / 512.f);
            float var = qq * (1.f / 512.f) - m * m;
            sMu[g * 64 + d] = m;
            sRs[g * 64 + d] = rsqrtf(var + EPSN);
        }
        const float* a0 = Ar + h * 4096;
        const float* a1 = Ai + h * 4096;
#pragma unroll
        for (int j = 0; j < 8; ++j) {
            int flat = t + 256 * j;
            int c = flat & 31, r = flat >> 5;
            sW0[r * 32 + c] = a0[r * 64 + eh * 32 + c];
            sW1[r * 32 + c] = a1[r * 64 + eh * 32 + c];
        }
        __syncthreads();
        {
            const int d = t & 63;
            const float m0 = sMu[d],      r0 = sRs[d],      g0 = grv[h * 64 + d], b0 = btrv[h * 64 + d];
            const float m1 = sMu[64 + d], r1 = sRs[64 + d], g1 = giv[h * 64 + d], bt1 = btiv[h * 64 + d];
#pragma unroll
            for (int j = 0; j < 8; ++j) {
                int row = (t >> 6) + 4 * j;  // 0..31
                int gidx = (hn * ROWS + rt * 32 + row) * 64 + d;
                float xr = wqr[gidx], xi = wqi[gidx];
                sX0[d * 32 + ((row + d) & 31)] = (xr - m0) * r0 * g0 + b0;
                sX1[d * 32 + ((row + d) & 31)] = (xi - m1) * r1 * g1 + bt1;
            }
        }
        __syncthreads();
        const int eq = t & 7, row = t >> 3;   // eq fast -> coalesced stores
        float v[4][4];
#pragma unroll
        for (int k = 0; k < 4; ++k)
#pragma unroll
            for (int j = 0; j < 4; ++j) v[k][j] = 0.f;
        for (int d = 0; d < 64; ++d) {
            float xr = sX0[d * 32 + ((row + d) & 31)];
            float xi = sX1[d * 32 + ((row + d) & 31)];
            float4 wr = *(const float4*)&sW0[d * 32 + eq * 4];
            float4 wi = *(const float4*)&sW1[d * 32 + eq * 4];
            v[0][0] = fmaf(xr, wr.x, v[0][0]); v[0][1] = fmaf(xr, wr.y, v[0][1]);
            v[0][2] = fmaf(xr, wr.z, v[0][2]); v[0][3] = fmaf(xr, wr.w, v[0][3]);
            v[1][0] = fmaf(xr, wi.x, v[1][0]); v[1][1] = fmaf(xr, wi.y, v[1][1]);
            v[1][2] = fmaf(xr, wi.z, v[1][2]); v[1][3] = fmaf(xr, wi.w, v[1][3]);
            v[2][0] = fmaf(xi, wr.x, v[2][0]); v[2][1] = fmaf(xi, wr.y, v[2][1]);
            v[2][2] = fmaf(xi, wr.z, v[2][2]); v[2][3] = fmaf(xi, wr.w, v[2][3]);
            v[3][0] = fmaf(xi, wi.x, v[3][0]); v[3][1] = fmaf(xi, wi.y, v[3][1]);
            v[3][2] = fmaf(xi, wi.z, v[3][2]); v[3][3] = fmaf(xi, wi.w, v[3][3]);
        }
        const int rowg = rt * 32 + row;
#pragma unroll
        for (int k = 0; k < 4; ++k) {
            float* o = Vout + (unsigned)k * 524288u + (hn * ROWS + rowg) * 64 + eh * 32 + eq * 4;
            *(float4*)o = make_float4(v[k][0], v[k][1], v[k][2], v[k][3]);
        }
        if (eh == 0 && t < 32) {
            const int rw = t;
            float cr = 0.f, ci = 0.f;
            for (int d = 0; d < 64; ++d) {
                float br = Abr[h * 64 + d], bi = Abi[h * 64 + d];
                float bm = br - bi, bp = br + bi;
                float xr = sX0[d * 32 + ((rw + d) & 31)];
                float xi = sX1[d * 32 + ((rw + d) & 31)];
                cr = fmaf(bm, xr, fmaf(-bp, xi, cr));
                ci = fmaf(bm, xi, fmaf( bp, xr, ci));
            }
            cR[hn * ROWS + rt * 32 + rw] = cr;
            cI[hn * ROWS + rt * 32 + rw] = ci;
        }
    } else {
        // ============================ role B: ac ============================
        float* sK0 = smem;            // [64][65]
        float* sK1 = smem + 4160;
        float* sQ0 = smem + 8320;     // [64][20]
        float* sQ1 = smem + 9600;
        float* sMu = smem + 10880;    // [4][64]
        float* sRs = smem + 11136;    // [4][64]
        const int idx = blockIdx.x - 512;
        const int qt = idx & 7, ph = (idx >> 3) & 1, hn = (idx >> 4) & 15;
        const int b = idx >> 8, h = hn >> 1;
        {
            int g = t >> 6, d = t & 63;
            int grp = g * 16 + hn;
            const float* ps = part + (unsigned)grp * 2048u + d;
            float s = 0.f, qq = 0.f;
#pragma unroll
            for (int r2 = 0; r2 < 16; ++r2) {
                s  += ps[r2 * 64];
                qq += ps[1024 + r2 * 64];
            }
            float m = s * (1.f / 512.f);
            float var = qq * (1.f / 512.f) - m * m;
            sMu[g * 64 + d] = m;
            sRs[g * 64 + d] = rsqrtf(var + EPSN);
        }
        __syncthreads();
#pragma unroll
        for (int j = 0; j < 4; ++j) {
            int flat4 = t + 256 * j;
            int word = flat4 * 4;
            int pp = word >> 6, ee = word & 63;
            int gidx = (hn * ROWS + (ph * 64 + pp) * 4 + b) * 64 + ee;
            float4 kr = *(const float4*)&wkr[gidx];
            float4 ki = *(const float4*)&wki[gidx];
            float4 m2 = *(const float4*)&sMu[128 + ee]; float4 r2 = *(const float4*)&sRs[128 + ee];
            float4 m3 = *(const float4*)&sMu[192 + ee]; float4 r3 = *(const float4*)&sRs[192 + ee];
            sK0[pp * 65 + ee + 0] = (kr.x - m2.x) * r2.x; sK0[pp * 65 + ee + 1] = (kr.y - m2.y) * r2.y;
            sK0[pp * 65 + ee + 2] = (kr.z - m2.z) * r2.z; sK0[pp * 65 + ee + 3] = (kr.w - m2.w) * r2.w;
            sK1[pp * 65 + ee + 0] = (ki.x - m3.x) * r3.x; sK1[pp * 65 + ee + 1] = (ki.y - m3.y) * r3.y;
            sK1[pp * 65 + ee + 2] = (ki.z - m3.z) * r3.z; sK1[pp * 65 + ee + 3] = (ki.w - m3.w) * r3.w;
        }
        {
            int word = t * 4;
            int qq = word >> 6, dd = word & 63;          // qq 0..15
            int gidx = (hn * ROWS + (qt * 16 + qq) * 4 + b) * 64 + dd;
            float4 xr = *(const float4*)&wqr[gidx];
            float4 xi = *(const float4*)&wqi[gidx];
            float4 m0 = *(const float4*)&sMu[dd];      float4 r0 = *(const float4*)&sRs[dd];
            float4 m1 = *(const float4*)&sMu[64 + dd]; float4 r1 = *(const float4*)&sRs[64 + dd];
            float4 g0 = *(const float4*)&gwr[h * 64 + dd]; float4 b0 = *(const float4*)&btwr[h * 64 + dd];
            float4 g1 = *(const float4*)&gwi[h * 64 + dd]; float4 b1 = *(const float4*)&btwi[h * 64 + dd];
            sQ0[(dd + 0) * 20 + qq] = fmaf((xr.x - m0.x) * r0.x, g0.x, b0.x);
            sQ0[(dd + 1) * 20 + qq] = fmaf((xr.y - m0.y) * r0.y, g0.y, b0.y);
            sQ0[(dd + 2) * 20 + qq] = fmaf((xr.z - m0.z) * r0.z, g0.z, b0.z);
            sQ0[(dd + 3) * 20 + qq] = fmaf((xr.w - m0.w) * r0.w, g0.w, b0.w);
            sQ1[(dd + 0) * 20 + qq] = fmaf((xi.x - m1.x) * r1.x, g1.x, b1.x);
            sQ1[(dd + 1) * 20 + qq] = fmaf((xi.y - m1.y) * r1.y, g1.y, b1.y);
            sQ1[(dd + 2) * 20 + qq] = fmaf((xi.z - m1.z) * r1.z, g1.z, b1.z);
            sQ1[(dd + 3) * 20 + qq] = fmaf((xi.w - m1.w) * r1.w, g1.w, b1.w);
        }
        __syncthreads();
        const int p = t & 63, qs = t >> 6;
        float acr[4], aci[4];
#pragma unroll
        for (int j = 0; j < 4; ++j) { acr[j] = 0.f; aci[j] = 0.f; }
        for (int e = 0; e < 64; ++e) {
            float kr = sK0[p * 65 + e], ki = sK1[p * 65 + e];
            float4 qr = *(const float4*)&sQ0[e * 20 + qs * 4];
            float4 qi = *(const float4*)&sQ1[e * 20 + qs * 4];
            acr[0] = fmaf(kr, qr.x, fmaf(-ki, qi.x, acr[0]));
            acr[1] = fmaf(kr, qr.y, fmaf(-ki, qi.y, acr[1]));
            acr[2] = fmaf(kr, qr.z, fmaf(-ki, qi.z, acr[2]));
            acr[3] = fmaf(kr, qr.w, fmaf(-ki, qi.w, acr[3]));
            aci[0] = fmaf(kr, qi.x, fmaf( ki, qr.x, aci[0]));
            aci[1] = fmaf(kr, qi.y, fmaf( ki, qr.y, aci[1]));
            aci[2] = fmaf(kr, qi.z, fmaf( ki, qr.z, aci[2]));
            aci[3] = fmaf(kr, qi.w, fmaf( ki, qr.w, aci[3]));
        }
#pragma unroll
        for (int j = 0; j < 4; ++j) {
            int qv = qt * 16 + qs * 4 + j;
            int oidx = ((hn * 128 + qv) * 4 + b) * 128 + ph * 64 + p;
            ACm[oidx] = sqrtf(fmaf(acr[j], acr[j], aci[j] * aci[j]));
        }
    }
}

// ---------------------------------------------------------------------------
// K3 (fused BD + softmax + PV): one block per (n,q).  grid 256, block 1024
// (16 waves/CU = 50% occ).  Two 512-thread groups (grp = t>>9) each process
// 4 p-tiles of 16, sharing one LDS Vv stage.  Per group: emb prefetched one
// tile ahead in registers; butterfly reduce; softmax over b via LDS; PV into
// registers.  Epilogue: intra-group then cross-group LDS merge.
// ---------------------------------------------------------------------------
__global__ __launch_bounds__(1024, 4) void k_bdpv(
    const float* __restrict__ ER, const float* __restrict__ EI,
    const float* __restrict__ Vv, const float* __restrict__ cR, const float* __restrict__ cI,
    const float* __restrict__ ACm,
    const float* __restrict__ Vr, const float* __restrict__ Vi,
    float* __restrict__ out)
{
    __shared__ __align__(16) float uS[10240];   // Vv stage [b][h][eo][k][4] stride 20; reused for merge
    __shared__ float sLg[1024];                 // logits [grp][plocal 16][h 8][b 4]
    __shared__ float sAf[1024];                 // aff
    const int t = threadIdx.x;
    const int grp = t >> 9;          // tile-group: tiles grp*4 .. grp*4+3
    const int w = (t >> 6) & 7;      // wave within group
    const int l = t & 63;
    const int b = w & 3, sub = w >> 2;
    const int eo = l & 15, pl = l >> 4;
    const int nq = blockIdx.x;
    const int n = nq >> 7, q = nq & 127;
    const int hh = (eo >> 1) & 7, jjo = eo & 1;
    const int plocal = sub * 8 + pl * 2 + jjo;   // 0..15 within a p-tile

    // emb address bases: qpo = Cq + p*256 ; pqo = Cp + p*32768
    const int Cq = (n * 128 + q) * 32768 + b * 64 + eo * 4;
    const int Cp = n * 4194304 + q * 256 + b * 64 + eo * 4;
    const unsigned Cacm = (unsigned)(((hh * 2 + n) * 128 + q) * 4 + b) * 128u;

    const float crx = cR[(hh * 2 + n) * ROWS + q * 4 + b];
    const float cix = cI[(hh * 2 + n) * ROWS + q * 4 + b];

    // ---- stage Vv: 2048 float4 over 1024 threads ----
#pragma unroll
    for (int it = 0; it < 2; ++it) {
        int flat = t + 1024 * it;                // float4 units
        int e4 = flat & 15, k = (flat >> 4) & 3, h = (flat >> 6) & 7, bb = flat >> 9;
        float4 x = *(const float4*)&Vv[(unsigned)k * 524288u
                                       + ((h * 2 + n) * ROWS + q * 4 + bb) * 64u + e4 * 4];
        *(float4*)&uS[(bb * 8 + h) * 320 + e4 * 20 + k * 4] = x;
    }

    // ---- prefetch first tile of this group ----
    float4 A[2], Bv_[2], C4[2], D4[2]; float acm;
    {
        int p0 = grp * 64 + sub * 8 + pl * 2;
#pragma unroll
        for (int jj = 0; jj < 2; ++jj) {
            int p = p0 + jj;
            A[jj]   = *(const float4*)(ER + Cq + p * 256);
            Bv_[jj] = *(const float4*)(EI + Cq + p * 256);
            C4[jj]  = *(const float4*)(ER + Cp + p * 32768);
            D4[jj]  = *(const float4*)(EI + Cp + p * 32768);
        }
        acm = ACm[Cacm + grp * 64 + plocal];
    }
    __syncthreads();     // Vv staged

    // PV role mapping (within group)
    const int half = (t >> 8) & 1, b3 = (t >> 6) & 3, d3 = t & 63;
    const float* vrB = Vr + (n * 512 + b3) * 64 + d3;   // + p*256
    const float* viB = Vi + (n * 512 + b3) * 64 + d3;
    float oR[8], oI[8];
#pragma unroll
    for (int hx = 0; hx < 8; ++hx) { oR[hx] = 0.f; oI[hx] = 0.f; }

    for (int tl = 0; tl < 4; ++tl) {
        const int tile = grp * 4 + tl;
        // ---- issue next-tile prefetch (in flight during compute) ----
        float4 An[2], Bn[2], Cn[2], Dn[2]; float acmn = 0.f;
        if (tl < 3) {
            int p0 = (tile + 1) * 16 + sub * 8 + pl * 2;
#pragma unroll
            for (int jj = 0; jj < 2; ++jj) {
                int p = p0 + jj;
                An[jj] = *(const float4*)(ER + Cq + p * 256);
                Bn[jj] = *(const float4*)(EI + Cq + p * 256);
                Cn[jj] = *(const float4*)(ER + Cp + p * 32768);
                Dn[jj] = *(const float4*)(EI + Cp + p * 32768);
            }
            acmn = ACm[Cacm + (tile + 1) * 16 + plocal];
        }

        // ---- BD dot products from current regs ----
        float accr[8][2], acci[8][2];
#pragma unroll
        for (int h = 0; h < 8; ++h)
#pragma unroll
            for (int j = 0; j < 2; ++j) { accr[h][j] = 0.f; acci[h][j] = 0.f; }
#pragma unroll
        for (int h = 0; h < 8; ++h) {
            const float* vb = &uS[(b * 8 + h) * 320 + eo * 20];
            float4 v1 = *(const float4*)(vb);
            float4 v2 = *(const float4*)(vb + 4);
            float4 v3 = *(const float4*)(vb + 8);
            float4 v4 = *(const float4*)(vb + 12);
#pragma unroll
            for (int jj = 0; jj < 2; ++jj) {
                DOT4 (accr[h][jj], A[jj],   v1);
                NDOT4(accr[h][jj], Bv_[jj], v2);
                NDOT4(accr[h][jj], C4[jj],  v4);
                NDOT4(accr[h][jj], D4[jj],  v3);
                DOT4 (acci[h][jj], A[jj],   v3);
                NDOT4(acci[h][jj], Bv_[jj], v4);
                DOT4 (acci[h][jj], C4[jj],  v2);
                DOT4 (acci[h][jj], D4[jj],  v1);
            }
        }

        // ---- ownership-split butterfly over eo (masks 8,4,2,1) ----
        float r4[4][2], i4[4][2];
#pragma unroll
        for (int h2 = 0; h2 < 4; ++h2)
#pragma unroll
        for (int j = 0; j < 2; ++j) {
            float ra = accr[h2][j]     + __shfl_xor(accr[h2][j], 8);
            float rb = accr[h2 + 4][j] + __shfl_xor(accr[h2 + 4][j], 8);
            r4[h2][j] = (eo & 8) ? rb : ra;
            float ia = acci[h2][j]     + __shfl_xor(acci[h2][j], 8);
            float ib = acci[h2 + 4][j] + __shfl_xor(acci[h2 + 4][j], 8);
            i4[h2][j] = (eo & 8) ? ib : ia;
        }
        float r2a[2][2], i2a[2][2];
#pragma unroll
        for (int h1 = 0; h1 < 2; ++h1)
#pragma unroll
        for (int j = 0; j < 2; ++j) {
            float ra = r4[h1][j]     + __shfl_xor(r4[h1][j], 4);
            float rb = r4[h1 + 2][j] + __shfl_xor(r4[h1 + 2][j], 4);
            r2a[h1][j] = (eo & 4) ? rb : ra;
            float ia = i4[h1][j]     + __shfl_xor(i4[h1][j], 4);
            float ib = i4[h1 + 2][j] + __shfl_xor(i4[h1 + 2][j], 4);
            i2a[h1][j] = (eo & 4) ? ib : ia;
        }
        float r1a[2], i1a[2];
#pragma unroll
        for (int j = 0; j < 2; ++j) {
            float ra = r2a[0][j] + __shfl_xor(r2a[0][j], 2);
            float rb = r2a[1][j] + __shfl_xor(r2a[1][j], 2);
            r1a[j] = (eo & 2) ? rb : ra;
            float ia = i2a[0][j] + __shfl_xor(i2a[0][j], 2);
            float ib = i2a[1][j] + __shfl_xor(i2a[1][j], 2);
            i1a[j] = (eo & 2) ? ib : ia;
        }
        float ra0 = r1a[0] + __shfl_xor(r1a[0], 1);
        float rb0 = r1a[1] + __shfl_xor(r1a[1], 1);
        float rr  = (eo & 1) ? rb0 : ra0;
        float ia0 = i1a[0] + __shfl_xor(i1a[0], 1);
        float ib0 = i1a[1] + __shfl_xor(i1a[1], 1);
        float ii  = (eo & 1) ? ib0 : ia0;

        float bdr = rr + crx, bdi = ii + cix;
        float lg = (acm + sqrtf(fmaf(bdr, bdr, bdi * bdi))) * TEMPER;
        sLg[grp * 512 + plocal * 32 + hh * 4 + b] = lg;
        __syncthreads();                  // bar1: logits visible
        {
            const float* lp = &sLg[grp * 512 + plocal * 32 + hh * 4];
            float l0 = lp[0], l1 = lp[1], l2 = lp[2], l3 = lp[3];
            float m = fmaxf(fmaxf(l0, l1), fmaxf(l2, l3));
            float s = __expf(l0 - m) + __expf(l1 - m) + __expf(l2 - m) + __expf(l3 - m);
            sAf[grp * 512 + plocal * 32 + hh * 4 + b] = __expf(lg - m) / s;
        }
        __syncthreads();                  // bar2: aff visible

        // ---- PV accumulation: each half handles 8 of the group's 16 p ----
#pragma unroll
        for (int pp = 0; pp < 8; ++pp) {
            int pg = tile * 16 + half * 8 + pp;
            float vr = vrB[pg * 256];
            float vi = viB[pg * 256];
            const float* af = &sAf[grp * 512 + (half * 8 + pp) * 32 + b3];
#pragma unroll
            for (int hx = 0; hx < 8; ++hx) {
                float a = af[hx * 4];
                oR[hx] = fmaf(a, vr, oR[hx]);
                oI[hx] = fmaf(a, vi, oI[hx]);
            }
        }

        // ---- rotate prefetch regs ----
#pragma unroll
        for (int jj = 0; jj < 2; ++jj) {
            A[jj] = An[jj]; Bv_[jj] = Bn[jj]; C4[jj] = Cn[jj]; D4[jj] = Dn[jj];
        }
        acm = acmn;
    }

    // ---- merge: round 1 intra-group (half1 -> half0), round 2 cross-group ----
    __syncthreads();
    if (half == 1) {
#pragma unroll
        for (int hx = 0; hx < 8; ++hx) {
            uS[grp * 4352 + (b3 * 64 + d3) * 17 + hx * 2]     = oR[hx];
            uS[grp * 4352 + (b3 * 64 + d3) * 17 + hx * 2 + 1] = oI[hx];
        }
    }
    __syncthreads();
    if (half == 0) {
#pragma unroll
        for (int hx = 0; hx < 8; ++hx) {
            oR[hx] += uS[grp * 4352 + (b3 * 64 + d3) * 17 + hx * 2];
            oI[hx] += uS[grp * 4352 + (b3 * 64 + d3) * 17 + hx * 2 + 1];
        }
    }
    __syncthreads();
    if (grp == 1 && half == 0) {
#pragma unroll
        for (int hx = 0; hx < 8; ++hx) {
            uS[(b3 * 64 + d3) * 17 + hx * 2]     = oR[hx];
            uS[(b3 * 64 + d3) * 17 + hx * 2 + 1] = oI[hx];
        }
    }
    __syncthreads();
    if (grp == 0 && half == 0) {
        const unsigned ob = (unsigned)((n * 128 + q) * 4 + b3) * 512u + d3;
#pragma unroll
        for (int hx = 0; hx < 8; ++hx) {
            float r = oR[hx] + uS[(b3 * 64 + d3) * 17 + hx * 2];
            float i = oI[hx] + uS[(b3 * 64 + d3) * 17 + hx * 2 + 1];
            out[ob + hx * 64]           = r;
            out[524288u + ob + hx * 64] = i;
        }
    }
}

// ---------------------------------------------------------------------------
extern "C" void kernel_launch(void* const* d_in, const int* in_sizes, int n_in,
                              void* d_out, int out_size, void* d_ws, size_t ws_size,
                              hipStream_t stream) {
    (void)in_sizes; (void)n_in; (void)out_size; (void)ws_size;
    const float* q_r  = (const float*)d_in[0];
    const float* q_i  = (const float*)d_in[1];
    const float* k_r  = (const float*)d_in[2];
    const float* k_i  = (const float*)d_in[3];
    const float* v_r  = (const float*)d_in[4];
    const float* v_i  = (const float*)d_in[5];
    const float* e_r  = (const float*)d_in[6];
    const float* e_i  = (const float*)d_in[7];
    const float* WKr_w  = (const float*)d_in[8];
    const float* WKi_w  = (const float*)d_in[10];
    const float* WKRr_w = (const float*)d_in[12];
    const float* WKRr_b = (const float*)d_in[13];
    const float* WKRi_w = (const float*)d_in[14];
    const float* WKRi_b = (const float*)d_in[15];
    const float* WQr_w  = (const float*)d_in[16];
    const float* WQi_w  = (const float*)d_in[18];
    const float* ww_r_g  = (const float*)d_in[20];
    const float* ww_r_bt = (const float*)d_in[21];
    const float* ww_i_g  = (const float*)d_in[22];
    const float* ww_i_bt = (const float*)d_in[23];
    const float* wr_r_g  = (const float*)d_in[24];
    const float* wr_r_bt = (const float*)d_in[25];
    const float* wr_i_g  = (const float*)d_in[26];
    const float* wr_i_bt = (const float*)d_in[27];
    float* ws  = (float*)d_ws;
    float* out = (float*)d_out;

    k_proj<<<dim3(16, 16, 2), 512, 0, stream>>>(q_r, q_i, k_r, k_i,
                                                WQr_w, WQi_w, WKr_w, WKi_w,
                                                ws, ws + PART_);
    k_mid<<<dim3(1536), 256, 0, stream>>>(ws + WQ_R, ws + WQ_I, ws + WK_R, ws + WK_I,
                                          ws + PART_,
                                          WKRr_w, WKRi_w, WKRr_b, WKRi_b,
                                          wr_r_g, wr_r_bt, wr_i_g, wr_i_bt,
                                          ww_r_g, ww_r_bt, ww_i_g, ww_i_bt,
                                          ws + VV_, ws + C_R_, ws + C_I_, ws + ACM_);
    k_bdpv<<<dim3(256), 1024, 0, stream>>>(e_r, e_i, ws + VV_, ws + C_R_, ws + C_I_,
                                           ws + ACM_, v_r, v_i, out);
}

// Round 4
// 229.233 us; speedup vs baseline: 1.1174x; 1.1174x over previous
//
#include <hip/hip_runtime.h>
#include <math.h>

// Problem constants
#define NH 8
#define DDIM 64
#define NN 2
#define QQ 128
#define PPDIM 128
#define BBD 4
#define ROWS 512           // Q*B == P*B
#define EPSN 1e-5f
#define TEMPER 30.0f

// Workspace layout (float offsets)
#define WQ_R 0u            // [H][N][512][64] rows = q*4+b
#define WQ_I 524288u
#define WK_R 1048576u      // rows = p*4+b
#define WK_I 1572864u
#define VV_  2105344u      // 4 x [H][N][512][64]  (v1,v2,v3,v4)
#define C_R_ 4202496u      // [H][N][512]
#define C_I_ 4210688u
#define ACM_ 4218880u      // [H][N][Q][B][P]  magnitude only
#define AFF_ 6316032u      // (dead this version; PART aliases here)
#define PART_ AFF_

#define DOT4(acc, s, v)  { acc = fmaf((s).x,(v).x,acc); acc = fmaf((s).y,(v).y,acc); acc = fmaf((s).z,(v).z,acc); acc = fmaf((s).w,(v).w,acc); }
#define NDOT4(acc, s, v) { acc = fmaf(-(s).x,(v).x,acc); acc = fmaf(-(s).y,(v).y,acc); acc = fmaf(-(s).z,(v).z,acc); acc = fmaf(-(s).w,(v).w,acc); }

// ---------------------------------------------------------------------------
// K1: complex projection (pre-norm) + fused InstanceNorm partial stats.
// grid (16 rowtiles, 16 hn, 2 qk), block 256  (R2-proven version)
// ---------------------------------------------------------------------------
__global__ __launch_bounds__(256) void k_proj(
    const float* __restrict__ qR, const float* __restrict__ qI,
    const float* __restrict__ kR, const float* __restrict__ kI,
    const float* __restrict__ WQr, const float* __restrict__ WQi,
    const float* __restrict__ WKr, const float* __restrict__ WKi,
    float* __restrict__ ws, float* __restrict__ part)
{
    __shared__ __align__(16) float sWT[2][64 * 64];     // transposed: [e][d]
    const int t  = threadIdx.x;
    const int rt = blockIdx.x;
    const int hn = blockIdx.y;
    const int z  = blockIdx.z;
    const int h = hn >> 1, n = hn & 1;
    const float* inR = z ? kR : qR;
    const float* inI = z ? kI : qI;
    const float* wr0 = (z ? WKr : WQr) + h * 4096;
    const float* wi0 = (z ? WKi : WQi) + h * 4096;
    float* outR = ws + (z ? WK_R : WQ_R);
    float* outI = ws + (z ? WK_I : WQ_I);
#pragma unroll
    for (int j = 0; j < 16; ++j) {
        int flat = t + 256 * j;
        int d = flat & 63, e = flat >> 6;
        sWT[0][e * 64 + d] = wr0[d * 64 + e];
        sWT[1][e * 64 + d] = wi0[d * 64 + e];
    }
    __syncthreads();
    const int row = t & 31, dq = t >> 5;     // dq 0..7, 8 outputs/thread
    const int rowg = rt * 32 + row;
    const float4* xr4 = (const float4*)(inR + (n * ROWS + rowg) * 64);
    const float4* xi4 = (const float4*)(inI + (n * ROWS + rowg) * 64);
    float ar[8], ai[8];
#pragma unroll
    for (int j = 0; j < 8; ++j) { ar[j] = 0.f; ai[j] = 0.f; }
    for (int ec = 0; ec < 16; ++ec) {
        float4 xrv = xr4[ec], xiv = xi4[ec];
        float xrs[4] = {xrv.x, xrv.y, xrv.z, xrv.w};
        float xis[4] = {xiv.x, xiv.y, xiv.z, xiv.w};
#pragma unroll
        for (int u = 0; u < 4; ++u) {
            int e = ec * 4 + u;
            const float4* wrp = (const float4*)&sWT[0][e * 64 + dq * 8];
            const float4* wip = (const float4*)&sWT[1][e * 64 + dq * 8];
            float xr = xrs[u], xi = xis[u];
#pragma unroll
            for (int j4 = 0; j4 < 2; ++j4) {
                float4 wr = wrp[j4], wi = wip[j4];
                ar[j4*4+0] = fmaf(xr, wr.x, fmaf(-xi, wi.x, ar[j4*4+0]));
                ar[j4*4+1] = fmaf(xr, wr.y, fmaf(-xi, wi.y, ar[j4*4+1]));
                ar[j4*4+2] = fmaf(xr, wr.z, fmaf(-xi, wi.z, ar[j4*4+2]));
                ar[j4*4+3] = fmaf(xr, wr.w, fmaf(-xi, wi.w, ar[j4*4+3]));
                ai[j4*4+0] = fmaf(xr, wi.x, fmaf( xi, wr.x, ai[j4*4+0]));
                ai[j4*4+1] = fmaf(xr, wi.y, fmaf( xi, wr.y, ai[j4*4+1]));
                ai[j4*4+2] = fmaf(xr, wi.z, fmaf( xi, wr.z, ai[j4*4+2]));
                ai[j4*4+3] = fmaf(xr, wi.w, fmaf( xi, wr.w, ai[j4*4+3]));
            }
        }
    }
    float* oR = outR + ((unsigned)hn * ROWS + rowg) * 64 + dq * 8;
    float* oI = outI + ((unsigned)hn * ROWS + rowg) * 64 + dq * 8;
#pragma unroll
    for (int j4 = 0; j4 < 2; ++j4) {
        ((float4*)oR)[j4] = make_float4(ar[j4*4+0], ar[j4*4+1], ar[j4*4+2], ar[j4*4+3]);
        ((float4*)oI)[j4] = make_float4(ai[j4*4+0], ai[j4*4+1], ai[j4*4+2], ai[j4*4+3]);
    }
    // ---- fused stats partials: sum over this block's 32 rows ----
    float s_r[8], q_r8[8], s_i[8], q_i8[8];
#pragma unroll
    for (int i = 0; i < 8; ++i) {
        s_r[i] = ar[i]; q_r8[i] = ar[i] * ar[i];
        s_i[i] = ai[i]; q_i8[i] = ai[i] * ai[i];
    }
#pragma unroll
    for (int m = 1; m <= 16; m <<= 1) {
#pragma unroll
        for (int i = 0; i < 8; ++i) {
            s_r[i]  += __shfl_xor(s_r[i],  m);
            q_r8[i] += __shfl_xor(q_r8[i], m);
            s_i[i]  += __shfl_xor(s_i[i],  m);
            q_i8[i] += __shfl_xor(q_i8[i], m);
        }
    }
    if ((t & 31) == 0) {
        const int gr = (z * 2) * 16 + hn;        // out_r tensor group
        const int gi = (z * 2 + 1) * 16 + hn;    // out_i tensor group
#pragma unroll
        for (int i = 0; i < 8; ++i) {
            int d = dq * 8 + i;
            part[(unsigned)gr * 2048u + rt * 64 + d]          = s_r[i];
            part[(unsigned)gr * 2048u + 1024 + rt * 64 + d]   = q_r8[i];
            part[(unsigned)gi * 2048u + rt * 64 + d]          = s_i[i];
            part[(unsigned)gi * 2048u + 1024 + rt * 64 + d]   = q_i8[i];
        }
    }
}

// ---------------------------------------------------------------------------
// K2 (fused): role A = v-vectors + bias dots (blocks 0..511)
//             role B = AC magnitude scores (blocks 512..1535)
// ---------------------------------------------------------------------------
__global__ __launch_bounds__(256) void k_mid(
    const float* __restrict__ wqr, const float* __restrict__ wqi,
    const float* __restrict__ wkr, const float* __restrict__ wki,
    const float* __restrict__ part,
    const float* __restrict__ Ar,  const float* __restrict__ Ai,
    const float* __restrict__ Abr, const float* __restrict__ Abi,
    const float* __restrict__ grv, const float* __restrict__ btrv,
    const float* __restrict__ giv, const float* __restrict__ btiv,
    const float* __restrict__ gwr, const float* __restrict__ btwr,
    const float* __restrict__ gwi, const float* __restrict__ btwi,
    float* __restrict__ Vout, float* __restrict__ cR, float* __restrict__ cI,
    float* __restrict__ ACm)
{
    __shared__ __align__(16) float smem[11392];
    const int t = threadIdx.x;
    if (blockIdx.x < 512) {
        // =========================== role A: vvec ===========================
        float* sW0 = smem;            // [64][32]
        float* sW1 = smem + 2048;
        float* sX0 = smem + 4096;     // [64][32] swizzled
        float* sX1 = smem + 6144;
        float* sMu = smem + 8192;     // [2][64]
        float* sRs = smem + 8320;     // [2][64]
        const int b1 = blockIdx.x;
        const int rt = b1 & 15, eh = (b1 >> 4) & 1, hn = b1 >> 5, h = hn >> 1;
        if (t < 128) {
            int g = t >> 6, d = t & 63;
            int grp = (g ? 16 : 0) + hn;
            const float* ps = part + (unsigned)grp * 2048u + d;
            float s = 0.f, qq = 0.f;
#pragma unroll
            for (int r2 = 0; r2 < 16; ++r2) {
                s  += ps[r2 * 64];
                qq += ps[1024 + r2 * 64];
            }
            float m = s * (1.f / 512.f);
            float var = qq * (1.f / 512.f) - m * m;
            sMu[g * 64 + d] = m;
            sRs[g * 64 + d] = rsqrtf(var + EPSN);
        }
        const float* a0 = Ar + h * 4096;
        const float* a1 = Ai + h * 4096;
#pragma unroll
        for (int j = 0; j < 8; ++j) {
            int flat = t + 256 * j;
            int c = flat & 31, r = flat >> 5;
            sW0[r * 32 + c] = a0[r * 64 + eh * 32 + c];
            sW1[r * 32 + c] = a1[r * 64 + eh * 32 + c];
        }
        __syncthreads();
        {
            const int d = t & 63;
            const float m0 = sMu[d],      r0 = sRs[d],      g0 = grv[h * 64 + d], b0 = btrv[h * 64 + d];
            const float m1 = sMu[64 + d], r1 = sRs[64 + d], g1 = giv[h * 64 + d], bt1 = btiv[h * 64 + d];
#pragma unroll
            for (int j = 0; j < 8; ++j) {
                int row = (t >> 6) + 4 * j;  // 0..31
                int gidx = (hn * ROWS + rt * 32 + row) * 64 + d;
                float xr = wqr[gidx], xi = wqi[gidx];
                sX0[d * 32 + ((row + d) & 31)] = (xr - m0) * r0 * g0 + b0;
                sX1[d * 32 + ((row + d) & 31)] = (xi - m1) * r1 * g1 + bt1;
            }
        }
        __syncthreads();
        const int eq = t & 7, row = t >> 3;   // eq fast -> coalesced stores
        float v[4][4];
#pragma unroll
        for (int k = 0; k < 4; ++k)
#pragma unroll
            for (int j = 0; j < 4; ++j) v[k][j] = 0.f;
        for (int d = 0; d < 64; ++d) {
            float xr = sX0[d * 32 + ((row + d) & 31)];
            float xi = sX1[d * 32 + ((row + d) & 31)];
            float4 wr = *(const float4*)&sW0[d * 32 + eq * 4];
            float4 wi = *(const float4*)&sW1[d * 32 + eq * 4];
            v[0][0] = fmaf(xr, wr.x, v[0][0]); v[0][1] = fmaf(xr, wr.y, v[0][1]);
            v[0][2] = fmaf(xr, wr.z, v[0][2]); v[0][3] = fmaf(xr, wr.w, v[0][3]);
            v[1][0] = fmaf(xr, wi.x, v[1][0]); v[1][1] = fmaf(xr, wi.y, v[1][1]);
            v[1][2] = fmaf(xr, wi.z, v[1][2]); v[1][3] = fmaf(xr, wi.w, v[1][3]);
            v[2][0] = fmaf(xi, wr.x, v[2][0]); v[2][1] = fmaf(xi, wr.y, v[2][1]);
            v[2][2] = fmaf(xi, wr.z, v[2][2]); v[2][3] = fmaf(xi, wr.w, v[2][3]);
            v[3][0] = fmaf(xi, wi.x, v[3][0]); v[3][1] = fmaf(xi, wi.y, v[3][1]);
            v[3][2] = fmaf(xi, wi.z, v[3][2]); v[3][3] = fmaf(xi, wi.w, v[3][3]);
        }
        const int rowg = rt * 32 + row;
#pragma unroll
        for (int k = 0; k < 4; ++k) {
            float* o = Vout + (unsigned)k * 524288u + (hn * ROWS + rowg) * 64 + eh * 32 + eq * 4;
            *(float4*)o = make_float4(v[k][0], v[k][1], v[k][2], v[k][3]);
        }
        if (eh == 0 && t < 32) {
            const int rw = t;
            float cr = 0.f, ci = 0.f;
            for (int d = 0; d < 64; ++d) {
                float br = Abr[h * 64 + d], bi = Abi[h * 64 + d];
                float bm = br - bi, bp = br + bi;
                float xr = sX0[d * 32 + ((rw + d) & 31)];
                float xi = sX1[d * 32 + ((rw + d) & 31)];
                cr = fmaf(bm, xr, fmaf(-bp, xi, cr));
                ci = fmaf(bm, xi, fmaf( bp, xr, ci));
            }
            cR[hn * ROWS + rt * 32 + rw] = cr;
            cI[hn * ROWS + rt * 32 + rw] = ci;
        }
    } else {
        // ============================ role B: ac ============================
        float* sK0 = smem;            // [64][65]
        float* sK1 = smem + 4160;
        float* sQ0 = smem + 8320;     // [64][20]
        float* sQ1 = smem + 9600;
        float* sMu = smem + 10880;    // [4][64]
        float* sRs = smem + 11136;    // [4][64]
        const int idx = blockIdx.x - 512;
        const int qt = idx & 7, ph = (idx >> 3) & 1, hn = (idx >> 4) & 15;
        const int b = idx >> 8, h = hn >> 1;
        {
            int g = t >> 6, d = t & 63;
            int grp = g * 16 + hn;
            const float* ps = part + (unsigned)grp * 2048u + d;
            float s = 0.f, qq = 0.f;
#pragma unroll
            for (int r2 = 0; r2 < 16; ++r2) {
                s  += ps[r2 * 64];
                qq += ps[1024 + r2 * 64];
            }
            float m = s * (1.f / 512.f);
            float var = qq * (1.f / 512.f) - m * m;
            sMu[g * 64 + d] = m;
            sRs[g * 64 + d] = rsqrtf(var + EPSN);
        }
        __syncthreads();
#pragma unroll
        for (int j = 0; j < 4; ++j) {
            int flat4 = t + 256 * j;
            int word = flat4 * 4;
            int pp = word >> 6, ee = word & 63;
            int gidx = (hn * ROWS + (ph * 64 + pp) * 4 + b) * 64 + ee;
            float4 kr = *(const float4*)&wkr[gidx];
            float4 ki = *(const float4*)&wki[gidx];
            float4 m2 = *(const float4*)&sMu[128 + ee]; float4 r2 = *(const float4*)&sRs[128 + ee];
            float4 m3 = *(const float4*)&sMu[192 + ee]; float4 r3 = *(const float4*)&sRs[192 + ee];
            sK0[pp * 65 + ee + 0] = (kr.x - m2.x) * r2.x; sK0[pp * 65 + ee + 1] = (kr.y - m2.y) * r2.y;
            sK0[pp * 65 + ee + 2] = (kr.z - m2.z) * r2.z; sK0[pp * 65 + ee + 3] = (kr.w - m2.w) * r2.w;
            sK1[pp * 65 + ee + 0] = (ki.x - m3.x) * r3.x; sK1[pp * 65 + ee + 1] = (ki.y - m3.y) * r3.y;
            sK1[pp * 65 + ee + 2] = (ki.z - m3.z) * r3.z; sK1[pp * 65 + ee + 3] = (ki.w - m3.w) * r3.w;
        }
        {
            int word = t * 4;
            int qq = word >> 6, dd = word & 63;          // qq 0..15
            int gidx = (hn * ROWS + (qt * 16 + qq) * 4 + b) * 64 + dd;
            float4 xr = *(const float4*)&wqr[gidx];
            float4 xi = *(const float4*)&wqi[gidx];
            float4 m0 = *(const float4*)&sMu[dd];      float4 r0 = *(const float4*)&sRs[dd];
            float4 m1 = *(const float4*)&sMu[64 + dd]; float4 r1 = *(const float4*)&sRs[64 + dd];
            float4 g0 = *(const float4*)&gwr[h * 64 + dd]; float4 b0 = *(const float4*)&btwr[h * 64 + dd];
            float4 g1 = *(const float4*)&gwi[h * 64 + dd]; float4 b1 = *(const float4*)&btwi[h * 64 + dd];
            sQ0[(dd + 0) * 20 + qq] = fmaf((xr.x - m0.x) * r0.x, g0.x, b0.x);
            sQ0[(dd + 1) * 20 + qq] = fmaf((xr.y - m0.y) * r0.y, g0.y, b0.y);
            sQ0[(dd + 2) * 20 + qq] = fmaf((xr.z - m0.z) * r0.z, g0.z, b0.z);
            sQ0[(dd + 3) * 20 + qq] = fmaf((xr.w - m0.w) * r0.w, g0.w, b0.w);
            sQ1[(dd + 0) * 20 + qq] = fmaf((xi.x - m1.x) * r1.x, g1.x, b1.x);
            sQ1[(dd + 1) * 20 + qq] = fmaf((xi.y - m1.y) * r1.y, g1.y, b1.y);
            sQ1[(dd + 2) * 20 + qq] = fmaf((xi.z - m1.z) * r1.z, g1.z, b1.z);
            sQ1[(dd + 3) * 20 + qq] = fmaf((xi.w - m1.w) * r1.w, g1.w, b1.w);
        }
        __syncthreads();
        const int p = t & 63, qs = t >> 6;
        float acr[4], aci[4];
#pragma unroll
        for (int j = 0; j < 4; ++j) { acr[j] = 0.f; aci[j] = 0.f; }
        for (int e = 0; e < 64; ++e) {
            float kr = sK0[p * 65 + e], ki = sK1[p * 65 + e];
            float4 qr = *(const float4*)&sQ0[e * 20 + qs * 4];
            float4 qi = *(const float4*)&sQ1[e * 20 + qs * 4];
            acr[0] = fmaf(kr, qr.x, fmaf(-ki, qi.x, acr[0]));
            acr[1] = fmaf(kr, qr.y, fmaf(-ki, qi.y, acr[1]));
            acr[2] = fmaf(kr, qr.z, fmaf(-ki, qi.z, acr[2]));
            acr[3] = fmaf(kr, qr.w, fmaf(-ki, qi.w, acr[3]));
            aci[0] = fmaf(kr, qi.x, fmaf( ki, qr.x, aci[0]));
            aci[1] = fmaf(kr, qi.y, fmaf( ki, qr.y, aci[1]));
            aci[2] = fmaf(kr, qi.z, fmaf( ki, qr.z, aci[2]));
            aci[3] = fmaf(kr, qi.w, fmaf( ki, qr.w, aci[3]));
        }
#pragma unroll
        for (int j = 0; j < 4; ++j) {
            int qv = qt * 16 + qs * 4 + j;
            int oidx = ((hn * 128 + qv) * 4 + b) * 128 + ph * 64 + p;
            ACm[oidx] = sqrtf(fmaf(acr[j], acr[j], aci[j] * aci[j]));
        }
    }
}

// ---------------------------------------------------------------------------
// K3 (fused BD + softmax + PV): grid (256 nq, 2 ph), block 512.
// Identical per-thread structure to the proven 52us R2 version (80 VGPR,
// no spills), but each block handles 4 p-tiles so 2 blocks/CU co-reside
// (16 waves/CU).  Output merged across the 2 ph blocks via atomicAdd into
// a zero-initialized out buffer.  sAf layout [p][b][h] -> PV reads float4.
// ---------------------------------------------------------------------------
__global__ __launch_bounds__(512, 2) void k_bdpv(
    const float* __restrict__ ER, const float* __restrict__ EI,
    const float* __restrict__ Vv, const float* __restrict__ cR, const float* __restrict__ cI,
    const float* __restrict__ ACm,
    const float* __restrict__ Vr, const float* __restrict__ Vi,
    float* __restrict__ out)
{
    __shared__ __align__(16) float uS[10240];   // Vv stage [b][h][eo][k][4] stride 20; reused for merge
    __shared__ float sLg[512];                  // logits [plocal 16][b 4][h 8]
    __shared__ float sAf[512];                  // aff
    const int t = threadIdx.x;
    const int w = t >> 6, l = t & 63;
    const int b = w & 3, sub = w >> 2;
    const int eo = l & 15, pl = l >> 4;
    const int nq = blockIdx.x;
    const int ph = blockIdx.y;       // 0/1: tiles ph*4 .. ph*4+3
    const int n = nq >> 7, q = nq & 127;
    const int hh = (eo >> 1) & 7, jjo = eo & 1;
    const int plocal = sub * 8 + pl * 2 + jjo;   // 0..15 within a p-tile

    // emb address bases: qpo = Cq + p*256 ; pqo = Cp + p*32768
    const int Cq = (n * 128 + q) * 32768 + b * 64 + eo * 4;
    const int Cp = n * 4194304 + q * 256 + b * 64 + eo * 4;
    const unsigned Cacm = (unsigned)(((hh * 2 + n) * 128 + q) * 4 + b) * 128u;

    const float crx = cR[(hh * 2 + n) * ROWS + q * 4 + b];
    const float cix = cI[(hh * 2 + n) * ROWS + q * 4 + b];

    // ---- stage Vv: 2048 float4 over 512 threads ----
#pragma unroll
    for (int it = 0; it < 4; ++it) {
        int flat = t + 512 * it;                 // float4 units
        int e4 = flat & 15, k = (flat >> 4) & 3, h = (flat >> 6) & 7, bb = flat >> 9;
        float4 x = *(const float4*)&Vv[(unsigned)k * 524288u
                                       + ((h * 2 + n) * ROWS + q * 4 + bb) * 64u + e4 * 4];
        *(float4*)&uS[(bb * 8 + h) * 320 + e4 * 20 + k * 4] = x;
    }

    // ---- prefetch first tile (tile index ph*4) ----
    float4 A[2], Bv_[2], C4[2], D4[2]; float acm;
    {
        int p0 = ph * 64 + sub * 8 + pl * 2;
#pragma unroll
        for (int jj = 0; jj < 2; ++jj) {
            int p = p0 + jj;
            A[jj]   = *(const float4*)(ER + Cq + p * 256);
            Bv_[jj] = *(const float4*)(EI + Cq + p * 256);
            C4[jj]  = *(const float4*)(ER + Cp + p * 32768);
            D4[jj]  = *(const float4*)(EI + Cp + p * 32768);
        }
        acm = ACm[Cacm + ph * 64 + plocal];
    }
    __syncthreads();     // Vv staged

    // PV role mapping
    const int half = t >> 8, b3 = (t >> 6) & 3, d3 = t & 63;
    const float* vrB = Vr + (n * 512 + b3) * 64 + d3;   // + p*256
    const float* viB = Vi + (n * 512 + b3) * 64 + d3;
    float oR[8], oI[8];
#pragma unroll
    for (int hx = 0; hx < 8; ++hx) { oR[hx] = 0.f; oI[hx] = 0.f; }

    for (int tl = 0; tl < 4; ++tl) {
        const int tile = ph * 4 + tl;
        // ---- issue next-tile prefetch (in flight during compute) ----
        float4 An[2], Bn[2], Cn[2], Dn[2]; float acmn = 0.f;
        if (tl < 3) {
            int p0 = (tile + 1) * 16 + sub * 8 + pl * 2;
#pragma unroll
            for (int jj = 0; jj < 2; ++jj) {
                int p = p0 + jj;
                An[jj] = *(const float4*)(ER + Cq + p * 256);
                Bn[jj] = *(const float4*)(EI + Cq + p * 256);
                Cn[jj] = *(const float4*)(ER + Cp + p * 32768);
                Dn[jj] = *(const float4*)(EI + Cp + p * 32768);
            }
            acmn = ACm[Cacm + (tile + 1) * 16 + plocal];
        }

        // ---- BD dot products from current regs ----
        float accr[8][2], acci[8][2];
#pragma unroll
        for (int h = 0; h < 8; ++h)
#pragma unroll
            for (int j = 0; j < 2; ++j) { accr[h][j] = 0.f; acci[h][j] = 0.f; }
#pragma unroll
        for (int h = 0; h < 8; ++h) {
            const float* vb = &uS[(b * 8 + h) * 320 + eo * 20];
            float4 v1 = *(const float4*)(vb);
            float4 v2 = *(const float4*)(vb + 4);
            float4 v3 = *(const float4*)(vb + 8);
            float4 v4 = *(const float4*)(vb + 12);
#pragma unroll
            for (int jj = 0; jj < 2; ++jj) {
                DOT4 (accr[h][jj], A[jj],   v1);
                NDOT4(accr[h][jj], Bv_[jj], v2);
                NDOT4(accr[h][jj], C4[jj],  v4);
                NDOT4(accr[h][jj], D4[jj],  v3);
                DOT4 (acci[h][jj], A[jj],   v3);
                NDOT4(acci[h][jj], Bv_[jj], v4);
                DOT4 (acci[h][jj], C4[jj],  v2);
                DOT4 (acci[h][jj], D4[jj],  v1);
            }
        }

        // ---- ownership-split butterfly over eo (masks 8,4,2,1) ----
        float r4[4][2], i4[4][2];
#pragma unroll
        for (int h2 = 0; h2 < 4; ++h2)
#pragma unroll
        for (int j = 0; j < 2; ++j) {
            float ra = accr[h2][j]     + __shfl_xor(accr[h2][j], 8);
            float rb = accr[h2 + 4][j] + __shfl_xor(accr[h2 + 4][j], 8);
            r4[h2][j] = (eo & 8) ? rb : ra;
            float ia = acci[h2][j]     + __shfl_xor(acci[h2][j], 8);
            float ib = acci[h2 + 4][j] + __shfl_xor(acci[h2 + 4][j], 8);
            i4[h2][j] = (eo & 8) ? ib : ia;
        }
        float r2a[2][2], i2a[2][2];
#pragma unroll
        for (int h1 = 0; h1 < 2; ++h1)
#pragma unroll
        for (int j = 0; j < 2; ++j) {
            float ra = r4[h1][j]     + __shfl_xor(r4[h1][j], 4);
            float rb = r4[h1 + 2][j] + __shfl_xor(r4[h1 + 2][j], 4);
            r2a[h1][j] = (eo & 4) ? rb : ra;
            float ia = i4[h1][j]     + __shfl_xor(i4[h1][j], 4);
            float ib = i4[h1 + 2][j] + __shfl_xor(i4[h1 + 2][j], 4);
            i2a[h1][j] = (eo & 4) ? ib : ia;
        }
        float r1a[2], i1a[2];
#pragma unroll
        for (int j = 0; j < 2; ++j) {
            float ra = r2a[0][j] + __shfl_xor(r2a[0][j], 2);
            float rb = r2a[1][j] + __shfl_xor(r2a[1][j], 2);
            r1a[j] = (eo & 2) ? rb : ra;
            float ia = i2a[0][j] + __shfl_xor(i2a[0][j], 2);
            float ib = i2a[1][j] + __shfl_xor(i2a[1][j], 2);
            i1a[j] = (eo & 2) ? ib : ia;
        }
        float ra0 = r1a[0] + __shfl_xor(r1a[0], 1);
        float rb0 = r1a[1] + __shfl_xor(r1a[1], 1);
        float rr  = (eo & 1) ? rb0 : ra0;
        float ia0 = i1a[0] + __shfl_xor(i1a[0], 1);
        float ib0 = i1a[1] + __shfl_xor(i1a[1], 1);
        float ii  = (eo & 1) ? ib0 : ia0;

        float bdr = rr + crx, bdi = ii + cix;
        float lg = (acm + sqrtf(fmaf(bdr, bdr, bdi * bdi))) * TEMPER;
        sLg[plocal * 32 + b * 8 + hh] = lg;
        __syncthreads();                  // bar1: logits visible
        {
            const float* lp = &sLg[plocal * 32 + hh];
            float l0 = lp[0], l1 = lp[8], l2 = lp[16], l3 = lp[24];
            float m = fmaxf(fmaxf(l0, l1), fmaxf(l2, l3));
            float s = __expf(l0 - m) + __expf(l1 - m) + __expf(l2 - m) + __expf(l3 - m);
            sAf[plocal * 32 + b * 8 + hh] = __expf(lg - m) / s;
        }
        __syncthreads();                  // bar2: aff visible

        // ---- PV accumulation: each half handles 8 of the 16 p ----
#pragma unroll
        for (int pp = 0; pp < 8; ++pp) {
            int pg = tile * 16 + half * 8 + pp;
            float vr = vrB[pg * 256];
            float vi = viB[pg * 256];
            const float* af = &sAf[(half * 8 + pp) * 32 + b3 * 8];
            float4 a0 = *(const float4*)af;
            float4 a1 = *(const float4*)(af + 4);
            oR[0] = fmaf(a0.x, vr, oR[0]); oR[1] = fmaf(a0.y, vr, oR[1]);
            oR[2] = fmaf(a0.z, vr, oR[2]); oR[3] = fmaf(a0.w, vr, oR[3]);
            oR[4] = fmaf(a1.x, vr, oR[4]); oR[5] = fmaf(a1.y, vr, oR[5]);
            oR[6] = fmaf(a1.z, vr, oR[6]); oR[7] = fmaf(a1.w, vr, oR[7]);
            oI[0] = fmaf(a0.x, vi, oI[0]); oI[1] = fmaf(a0.y, vi, oI[1]);
            oI[2] = fmaf(a0.z, vi, oI[2]); oI[3] = fmaf(a0.w, vi, oI[3]);
            oI[4] = fmaf(a1.x, vi, oI[4]); oI[5] = fmaf(a1.y, vi, oI[5]);
            oI[6] = fmaf(a1.z, vi, oI[6]); oI[7] = fmaf(a1.w, vi, oI[7]);
        }

        // ---- rotate prefetch regs ----
#pragma unroll
        for (int jj = 0; jj < 2; ++jj) {
            A[jj] = An[jj]; Bv_[jj] = Bn[jj]; C4[jj] = Cn[jj]; D4[jj] = Dn[jj];
        }
        acm = acmn;
    }

    // ---- cross-half reduce via dead Vv region, then atomicAdd to out ----
    __syncthreads();
    if (half == 1) {
#pragma unroll
        for (int hx = 0; hx < 8; ++hx) {
            uS[(b3 * 64 + d3) * 17 + hx * 2]     = oR[hx];
            uS[(b3 * 64 + d3) * 17 + hx * 2 + 1] = oI[hx];
        }
    }
    __syncthreads();
    if (half == 0) {
        const unsigned ob = (unsigned)((n * 128 + q) * 4 + b3) * 512u + d3;
#pragma unroll
        for (int hx = 0; hx < 8; ++hx) {
            float r = oR[hx] + uS[(b3 * 64 + d3) * 17 + hx * 2];
            float i = oI[hx] + uS[(b3 * 64 + d3) * 17 + hx * 2 + 1];
            atomicAdd(&out[ob + hx * 64], r);
            atomicAdd(&out[524288u + ob + hx * 64], i);
        }
    }
}

// ---------------------------------------------------------------------------
extern "C" void kernel_launch(void* const* d_in, const int* in_sizes, int n_in,
                              void* d_out, int out_size, void* d_ws, size_t ws_size,
                              hipStream_t stream) {
    (void)in_sizes; (void)n_in; (void)ws_size;
    const float* q_r  = (const float*)d_in[0];
    const float* q_i  = (const float*)d_in[1];
    const float* k_r  = (const float*)d_in[2];
    const float* k_i  = (const float*)d_in[3];
    const float* v_r  = (const float*)d_in[4];
    const float* v_i  = (const float*)d_in[5];
    const float* e_r  = (const float*)d_in[6];
    const float* e_i  = (const float*)d_in[7];
    const float* WKr_w  = (const float*)d_in[8];
    const float* WKi_w  = (const float*)d_in[10];
    const float* WKRr_w = (const float*)d_in[12];
    const float* WKRr_b = (const float*)d_in[13];
    const float* WKRi_w = (const float*)d_in[14];
    const float* WKRi_b = (const float*)d_in[15];
    const float* WQr_w  = (const float*)d_in[16];
    const float* WQi_w  = (const float*)d_in[18];
    const float* ww_r_g  = (const float*)d_in[20];
    const float* ww_r_bt = (const float*)d_in[21];
    const float* ww_i_g  = (const float*)d_in[22];
    const float* ww_i_bt = (const float*)d_in[23];
    const float* wr_r_g  = (const float*)d_in[24];
    const float* wr_r_bt = (const float*)d_in[25];
    const float* wr_i_g  = (const float*)d_in[26];
    const float* wr_i_bt = (const float*)d_in[27];
    float* ws  = (float*)d_ws;
    float* out = (float*)d_out;

    // zero the output (k_bdpv accumulates via atomicAdd from 2 blocks/(n,q))
    hipMemsetAsync(d_out, 0, (size_t)out_size, stream);

    k_proj<<<dim3(16, 16, 2), 256, 0, stream>>>(q_r, q_i, k_r, k_i,
                                                WQr_w, WQi_w, WKr_w, WKi_w,
                                                ws, ws + PART_);
    k_mid<<<dim3(1536), 256, 0, stream>>>(ws + WQ_R, ws + WQ_I, ws + WK_R, ws + WK_I,
                                          ws + PART_,
                                          WKRr_w, WKRi_w, WKRr_b, WKRi_b,
                                          wr_r_g, wr_r_bt, wr_i_g, wr_i_bt,
                                          ww_r_g, ww_r_bt, ww_i_g, ww_i_bt,
                                          ws + VV_, ws + C_R_, ws + C_I_, ws + ACM_);
    k_bdpv<<<dim3(256, 2), 512, 0, stream>>>(e_r, e_i, ws + VV_, ws + C_R_, ws + C_I_,
                                             ws + ACM_, v_r, v_i, out);
}

// Round 5
// 216.681 us; speedup vs baseline: 1.1821x; 1.0579x over previous
//
#include <hip/hip_runtime.h>
#include <math.h>

// Problem constants
#define NH 8
#define DDIM 64
#define NN 2
#define QQ 128
#define PPDIM 128
#define BBD 4
#define ROWS 512           // Q*B == P*B
#define EPSN 1e-5f
#define TEMPER 30.0f

// Workspace layout (float offsets)
#define WQ_R 0u            // [H][N][512][64] rows = q*4+b
#define WQ_I 524288u
#define WK_R 1048576u      // rows = p*4+b
#define WK_I 1572864u
#define VV_  2105344u      // 4 x [H][N][512][64]  (v1,v2,v3,v4)
#define C_R_ 4202496u      // [H][N][512]
#define C_I_ 4210688u
#define ACM_ 4218880u      // [H][N][Q][B][P]  magnitude only
#define AFF_ 6316032u      // [N][Q][B][H][P]
// stats partials live in AFF region (dead until k_bd): [grp 64][sv 2][rt 16][d 64]
#define PART_ AFF_

#define DOT4(acc, s, v)  { acc = fmaf((s).x,(v).x,acc); acc = fmaf((s).y,(v).y,acc); acc = fmaf((s).z,(v).z,acc); acc = fmaf((s).w,(v).w,acc); }
#define NDOT4(acc, s, v) { acc = fmaf(-(s).x,(v).x,acc); acc = fmaf(-(s).y,(v).y,acc); acc = fmaf(-(s).z,(v).z,acc); acc = fmaf(-(s).w,(v).w,acc); }

// ---------------------------------------------------------------------------
// K1: complex projection (pre-norm) + fused InstanceNorm partial stats.
// Karatsuba: P1=Xr·Wr, P2=Xi·Wi, P3=(Xr+Xi)·(Wr+Wi); out_r=P1-P2,
// out_i=P3-P1-P2  -> 24 fma/e vs 32.  grid (16 rt, 16 hn, 2 qk), block 256.
// ---------------------------------------------------------------------------
__global__ __launch_bounds__(256) void k_proj(
    const float* __restrict__ qR, const float* __restrict__ qI,
    const float* __restrict__ kR, const float* __restrict__ kI,
    const float* __restrict__ WQr, const float* __restrict__ WQi,
    const float* __restrict__ WKr, const float* __restrict__ WKi,
    float* __restrict__ ws, float* __restrict__ part)
{
    __shared__ __align__(16) float sWT[3][64 * 64];     // transposed: Wr^T, Wi^T, (Wr+Wi)^T
    const int t  = threadIdx.x;
    const int rt = blockIdx.x;
    const int hn = blockIdx.y;
    const int z  = blockIdx.z;
    const int h = hn >> 1, n = hn & 1;
    const float* inR = z ? kR : qR;
    const float* inI = z ? kI : qI;
    const float* wr0 = (z ? WKr : WQr) + h * 4096;
    const float* wi0 = (z ? WKi : WQi) + h * 4096;
    float* outR = ws + (z ? WK_R : WQ_R);
    float* outI = ws + (z ? WK_I : WQ_I);
#pragma unroll
    for (int j = 0; j < 16; ++j) {
        int flat = t + 256 * j;
        int d = flat & 63, e = flat >> 6;
        float a = wr0[d * 64 + e];
        float b = wi0[d * 64 + e];
        sWT[0][e * 64 + d] = a;
        sWT[1][e * 64 + d] = b;
        sWT[2][e * 64 + d] = a + b;
    }
    __syncthreads();
    const int row = t & 31, dq = t >> 5;     // dq 0..7, 8 outputs/thread
    const int rowg = rt * 32 + row;
    const float4* xr4 = (const float4*)(inR + (n * ROWS + rowg) * 64);
    const float4* xi4 = (const float4*)(inI + (n * ROWS + rowg) * 64);
    float p1[8], p2[8], p3[8];
#pragma unroll
    for (int j = 0; j < 8; ++j) { p1[j] = 0.f; p2[j] = 0.f; p3[j] = 0.f; }
    for (int ec = 0; ec < 16; ++ec) {
        float4 xrv = xr4[ec], xiv = xi4[ec];
        float xrs[4] = {xrv.x, xrv.y, xrv.z, xrv.w};
        float xis[4] = {xiv.x, xiv.y, xiv.z, xiv.w};
#pragma unroll
        for (int u = 0; u < 4; ++u) {
            int e = ec * 4 + u;
            const float4* wrp = (const float4*)&sWT[0][e * 64 + dq * 8];
            const float4* wip = (const float4*)&sWT[1][e * 64 + dq * 8];
            const float4* wsp = (const float4*)&sWT[2][e * 64 + dq * 8];
            float xr = xrs[u], xi = xis[u], xs = xr + xi;
#pragma unroll
            for (int j4 = 0; j4 < 2; ++j4) {
                float4 wr = wrp[j4], wi = wip[j4], wsv = wsp[j4];
                p1[j4*4+0] = fmaf(xr, wr.x, p1[j4*4+0]);
                p1[j4*4+1] = fmaf(xr, wr.y, p1[j4*4+1]);
                p1[j4*4+2] = fmaf(xr, wr.z, p1[j4*4+2]);
                p1[j4*4+3] = fmaf(xr, wr.w, p1[j4*4+3]);
                p2[j4*4+0] = fmaf(xi, wi.x, p2[j4*4+0]);
                p2[j4*4+1] = fmaf(xi, wi.y, p2[j4*4+1]);
                p2[j4*4+2] = fmaf(xi, wi.z, p2[j4*4+2]);
                p2[j4*4+3] = fmaf(xi, wi.w, p2[j4*4+3]);
                p3[j4*4+0] = fmaf(xs, wsv.x, p3[j4*4+0]);
                p3[j4*4+1] = fmaf(xs, wsv.y, p3[j4*4+1]);
                p3[j4*4+2] = fmaf(xs, wsv.z, p3[j4*4+2]);
                p3[j4*4+3] = fmaf(xs, wsv.w, p3[j4*4+3]);
            }
        }
    }
    float ar[8], ai[8];
#pragma unroll
    for (int j = 0; j < 8; ++j) {
        ar[j] = p1[j] - p2[j];
        ai[j] = p3[j] - p1[j] - p2[j];
    }
    float* oR = outR + ((unsigned)hn * ROWS + rowg) * 64 + dq * 8;
    float* oI = outI + ((unsigned)hn * ROWS + rowg) * 64 + dq * 8;
#pragma unroll
    for (int j4 = 0; j4 < 2; ++j4) {
        ((float4*)oR)[j4] = make_float4(ar[j4*4+0], ar[j4*4+1], ar[j4*4+2], ar[j4*4+3]);
        ((float4*)oI)[j4] = make_float4(ai[j4*4+0], ai[j4*4+1], ai[j4*4+2], ai[j4*4+3]);
    }
    // ---- fused stats partials: sum over this block's 32 rows ----
    float s_r[8], q_r8[8], s_i[8], q_i8[8];
#pragma unroll
    for (int i = 0; i < 8; ++i) {
        s_r[i] = ar[i]; q_r8[i] = ar[i] * ar[i];
        s_i[i] = ai[i]; q_i8[i] = ai[i] * ai[i];
    }
#pragma unroll
    for (int m = 1; m <= 16; m <<= 1) {
#pragma unroll
        for (int i = 0; i < 8; ++i) {
            s_r[i]  += __shfl_xor(s_r[i],  m);
            q_r8[i] += __shfl_xor(q_r8[i], m);
            s_i[i]  += __shfl_xor(s_i[i],  m);
            q_i8[i] += __shfl_xor(q_i8[i], m);
        }
    }
    if ((t & 31) == 0) {
        const int gr = (z * 2) * 16 + hn;        // out_r tensor group
        const int gi = (z * 2 + 1) * 16 + hn;    // out_i tensor group
#pragma unroll
        for (int i = 0; i < 8; ++i) {
            int d = dq * 8 + i;
            part[(unsigned)gr * 2048u + rt * 64 + d]          = s_r[i];
            part[(unsigned)gr * 2048u + 1024 + rt * 64 + d]   = q_r8[i];
            part[(unsigned)gi * 2048u + rt * 64 + d]          = s_i[i];
            part[(unsigned)gi * 2048u + 1024 + rt * 64 + d]   = q_i8[i];
        }
    }
}

// ---------------------------------------------------------------------------
// K2 (fused): role A = v-vectors + bias dots (blocks 0..511)
//             role B = AC magnitude scores with Karatsuba (blocks 512..1535)
// ---------------------------------------------------------------------------
__global__ __launch_bounds__(256) void k_mid(
    const float* __restrict__ wqr, const float* __restrict__ wqi,
    const float* __restrict__ wkr, const float* __restrict__ wki,
    const float* __restrict__ part,
    const float* __restrict__ Ar,  const float* __restrict__ Ai,
    const float* __restrict__ Abr, const float* __restrict__ Abi,
    const float* __restrict__ grv, const float* __restrict__ btrv,
    const float* __restrict__ giv, const float* __restrict__ btiv,
    const float* __restrict__ gwr, const float* __restrict__ btwr,
    const float* __restrict__ gwi, const float* __restrict__ btwi,
    float* __restrict__ Vout, float* __restrict__ cR, float* __restrict__ cI,
    float* __restrict__ ACm)
{
    __shared__ __align__(16) float smem[12672];
    const int t = threadIdx.x;
    if (blockIdx.x < 512) {
        // =========================== role A: vvec ===========================
        float* sW0 = smem;            // [64][32]
        float* sW1 = smem + 2048;
        float* sX0 = smem + 4096;     // [64][32] swizzled
        float* sX1 = smem + 6144;
        float* sMu = smem + 8192;     // [2][64]
        float* sRs = smem + 8320;     // [2][64]
        const int b1 = blockIdx.x;
        const int rt = b1 & 15, eh = (b1 >> 4) & 1, hn = b1 >> 5, h = hn >> 1;
        if (t < 128) {
            int g = t >> 6, d = t & 63;
            int grp = (g ? 16 : 0) + hn;
            const float* ps = part + (unsigned)grp * 2048u + d;
            float s = 0.f, qq = 0.f;
#pragma unroll
            for (int r2 = 0; r2 < 16; ++r2) {
                s  += ps[r2 * 64];
                qq += ps[1024 + r2 * 64];
            }
            float m = s * (1.f / 512.f);
            float var = qq * (1.f / 512.f) - m * m;
            sMu[g * 64 + d] = m;
            sRs[g * 64 + d] = rsqrtf(var + EPSN);
        }
        const float* a0 = Ar + h * 4096;
        const float* a1 = Ai + h * 4096;
#pragma unroll
        for (int j = 0; j < 8; ++j) {
            int flat = t + 256 * j;
            int c = flat & 31, r = flat >> 5;
            sW0[r * 32 + c] = a0[r * 64 + eh * 32 + c];
            sW1[r * 32 + c] = a1[r * 64 + eh * 32 + c];
        }
        __syncthreads();
        {
            const int d = t & 63;
            const float m0 = sMu[d],      r0 = sRs[d],      g0 = grv[h * 64 + d], b0 = btrv[h * 64 + d];
            const float m1 = sMu[64 + d], r1 = sRs[64 + d], g1 = giv[h * 64 + d], bt1 = btiv[h * 64 + d];
#pragma unroll
            for (int j = 0; j < 8; ++j) {
                int row = (t >> 6) + 4 * j;  // 0..31
                int gidx = (hn * ROWS + rt * 32 + row) * 64 + d;
                float xr = wqr[gidx], xi = wqi[gidx];
                sX0[d * 32 + ((row + d) & 31)] = (xr - m0) * r0 * g0 + b0;
                sX1[d * 32 + ((row + d) & 31)] = (xi - m1) * r1 * g1 + bt1;
            }
        }
        __syncthreads();
        const int eq = t & 7, row = t >> 3;   // eq fast -> coalesced stores
        float v[4][4];
#pragma unroll
        for (int k = 0; k < 4; ++k)
#pragma unroll
            for (int j = 0; j < 4; ++j) v[k][j] = 0.f;
        for (int d = 0; d < 64; ++d) {
            float xr = sX0[d * 32 + ((row + d) & 31)];
            float xi = sX1[d * 32 + ((row + d) & 31)];
            float4 wr = *(const float4*)&sW0[d * 32 + eq * 4];
            float4 wi = *(const float4*)&sW1[d * 32 + eq * 4];
            v[0][0] = fmaf(xr, wr.x, v[0][0]); v[0][1] = fmaf(xr, wr.y, v[0][1]);
            v[0][2] = fmaf(xr, wr.z, v[0][2]); v[0][3] = fmaf(xr, wr.w, v[0][3]);
            v[1][0] = fmaf(xr, wi.x, v[1][0]); v[1][1] = fmaf(xr, wi.y, v[1][1]);
            v[1][2] = fmaf(xr, wi.z, v[1][2]); v[1][3] = fmaf(xr, wi.w, v[1][3]);
            v[2][0] = fmaf(xi, wr.x, v[2][0]); v[2][1] = fmaf(xi, wr.y, v[2][1]);
            v[2][2] = fmaf(xi, wr.z, v[2][2]); v[2][3] = fmaf(xi, wr.w, v[2][3]);
            v[3][0] = fmaf(xi, wi.x, v[3][0]); v[3][1] = fmaf(xi, wi.y, v[3][1]);
            v[3][2] = fmaf(xi, wi.z, v[3][2]); v[3][3] = fmaf(xi, wi.w, v[3][3]);
        }
        const int rowg = rt * 32 + row;
#pragma unroll
        for (int k = 0; k < 4; ++k) {
            float* o = Vout + (unsigned)k * 524288u + (hn * ROWS + rowg) * 64 + eh * 32 + eq * 4;
            *(float4*)o = make_float4(v[k][0], v[k][1], v[k][2], v[k][3]);
        }
        if (eh == 0 && t < 32) {
            const int rw = t;
            float cr = 0.f, ci = 0.f;
            for (int d = 0; d < 64; ++d) {
                float br = Abr[h * 64 + d], bi = Abi[h * 64 + d];
                float bm = br - bi, bp = br + bi;
                float xr = sX0[d * 32 + ((rw + d) & 31)];
                float xi = sX1[d * 32 + ((rw + d) & 31)];
                cr = fmaf(bm, xr, fmaf(-bp, xi, cr));
                ci = fmaf(bm, xi, fmaf( bp, xr, ci));
            }
            cR[hn * ROWS + rt * 32 + rw] = cr;
            cI[hn * ROWS + rt * 32 + rw] = ci;
        }
    } else {
        // ============================ role B: ac ============================
        float* sK0 = smem;            // [64][65]
        float* sK1 = smem + 4160;
        float* sQ0 = smem + 8320;     // [64][20]
        float* sQ1 = smem + 9600;
        float* sMu = smem + 10880;    // [4][64]
        float* sRs = smem + 11136;    // [4][64]
        float* sQs = smem + 11392;    // [64][20]  (q_r+q_i) for Karatsuba
        const int idx = blockIdx.x - 512;
        const int qt = idx & 7, ph = (idx >> 3) & 1, hn = (idx >> 4) & 15;
        const int b = idx >> 8, h = hn >> 1;
        {
            int g = t >> 6, d = t & 63;
            int grp = g * 16 + hn;
            const float* ps = part + (unsigned)grp * 2048u + d;
            float s = 0.f, qq = 0.f;
#pragma unroll
            for (int r2 = 0; r2 < 16; ++r2) {
                s  += ps[r2 * 64];
                qq += ps[1024 + r2 * 64];
            }
            float m = s * (1.f / 512.f);
            float var = qq * (1.f / 512.f) - m * m;
            sMu[g * 64 + d] = m;
            sRs[g * 64 + d] = rsqrtf(var + EPSN);
        }
        __syncthreads();
#pragma unroll
        for (int j = 0; j < 4; ++j) {
            int flat4 = t + 256 * j;
            int word = flat4 * 4;
            int pp = word >> 6, ee = word & 63;
            int gidx = (hn * ROWS + (ph * 64 + pp) * 4 + b) * 64 + ee;
            float4 kr = *(const float4*)&wkr[gidx];
            float4 ki = *(const float4*)&wki[gidx];
            float4 m2 = *(const float4*)&sMu[128 + ee]; float4 r2 = *(const float4*)&sRs[128 + ee];
            float4 m3 = *(const float4*)&sMu[192 + ee]; float4 r3 = *(const float4*)&sRs[192 + ee];
            sK0[pp * 65 + ee + 0] = (kr.x - m2.x) * r2.x; sK0[pp * 65 + ee + 1] = (kr.y - m2.y) * r2.y;
            sK0[pp * 65 + ee + 2] = (kr.z - m2.z) * r2.z; sK0[pp * 65 + ee + 3] = (kr.w - m2.w) * r2.w;
            sK1[pp * 65 + ee + 0] = (ki.x - m3.x) * r3.x; sK1[pp * 65 + ee + 1] = (ki.y - m3.y) * r3.y;
            sK1[pp * 65 + ee + 2] = (ki.z - m3.z) * r3.z; sK1[pp * 65 + ee + 3] = (ki.w - m3.w) * r3.w;
        }
        {
            int word = t * 4;
            int qq = word >> 6, dd = word & 63;          // qq 0..15
            int gidx = (hn * ROWS + (qt * 16 + qq) * 4 + b) * 64 + dd;
            float4 xr = *(const float4*)&wqr[gidx];
            float4 xi = *(const float4*)&wqi[gidx];
            float4 m0 = *(const float4*)&sMu[dd];      float4 r0 = *(const float4*)&sRs[dd];
            float4 m1 = *(const float4*)&sMu[64 + dd]; float4 r1 = *(const float4*)&sRs[64 + dd];
            float4 g0 = *(const float4*)&gwr[h * 64 + dd]; float4 b0 = *(const float4*)&btwr[h * 64 + dd];
            float4 g1 = *(const float4*)&gwi[h * 64 + dd]; float4 b1 = *(const float4*)&btwi[h * 64 + dd];
            float q0x = fmaf((xr.x - m0.x) * r0.x, g0.x, b0.x);
            float q0y = fmaf((xr.y - m0.y) * r0.y, g0.y, b0.y);
            float q0z = fmaf((xr.z - m0.z) * r0.z, g0.z, b0.z);
            float q0w = fmaf((xr.w - m0.w) * r0.w, g0.w, b0.w);
            float q1x = fmaf((xi.x - m1.x) * r1.x, g1.x, b1.x);
            float q1y = fmaf((xi.y - m1.y) * r1.y, g1.y, b1.y);
            float q1z = fmaf((xi.z - m1.z) * r1.z, g1.z, b1.z);
            float q1w = fmaf((xi.w - m1.w) * r1.w, g1.w, b1.w);
            sQ0[(dd + 0) * 20 + qq] = q0x; sQ0[(dd + 1) * 20 + qq] = q0y;
            sQ0[(dd + 2) * 20 + qq] = q0z; sQ0[(dd + 3) * 20 + qq] = q0w;
            sQ1[(dd + 0) * 20 + qq] = q1x; sQ1[(dd + 1) * 20 + qq] = q1y;
            sQ1[(dd + 2) * 20 + qq] = q1z; sQ1[(dd + 3) * 20 + qq] = q1w;
            sQs[(dd + 0) * 20 + qq] = q0x + q1x; sQs[(dd + 1) * 20 + qq] = q0y + q1y;
            sQs[(dd + 2) * 20 + qq] = q0z + q1z; sQs[(dd + 3) * 20 + qq] = q0w + q1w;
        }
        __syncthreads();
        const int p = t & 63, qs = t >> 6;
        // Karatsuba accumulators: P1 = kr·qr, P2 = ki·qi, P3 = (kr+ki)·(qr+qi)
        float p1a[4], p2a[4], p3a[4];
#pragma unroll
        for (int j = 0; j < 4; ++j) { p1a[j] = 0.f; p2a[j] = 0.f; p3a[j] = 0.f; }
        for (int e = 0; e < 64; ++e) {
            float kr = sK0[p * 65 + e], ki = sK1[p * 65 + e];
            float ks = kr + ki;
            float4 qr  = *(const float4*)&sQ0[e * 20 + qs * 4];
            float4 qi  = *(const float4*)&sQ1[e * 20 + qs * 4];
            float4 qsv = *(const float4*)&sQs[e * 20 + qs * 4];
            p1a[0] = fmaf(kr, qr.x, p1a[0]); p1a[1] = fmaf(kr, qr.y, p1a[1]);
            p1a[2] = fmaf(kr, qr.z, p1a[2]); p1a[3] = fmaf(kr, qr.w, p1a[3]);
            p2a[0] = fmaf(ki, qi.x, p2a[0]); p2a[1] = fmaf(ki, qi.y, p2a[1]);
            p2a[2] = fmaf(ki, qi.z, p2a[2]); p2a[3] = fmaf(ki, qi.w, p2a[3]);
            p3a[0] = fmaf(ks, qsv.x, p3a[0]); p3a[1] = fmaf(ks, qsv.y, p3a[1]);
            p3a[2] = fmaf(ks, qsv.z, p3a[2]); p3a[3] = fmaf(ks, qsv.w, p3a[3]);
        }
#pragma unroll
        for (int j = 0; j < 4; ++j) {
            float acr = p1a[j] - p2a[j];
            float aci = p3a[j] - p1a[j] - p2a[j];
            int qv = qt * 16 + qs * 4 + j;
            int oidx = ((hn * 128 + qv) * 4 + b) * 128 + ph * 64 + p;
            ACm[oidx] = sqrtf(fmaf(acr, acr, aci * aci));
        }
    }
}

// ---------------------------------------------------------------------------
// K5 (R1-proven): fused BD + AC + affinity + softmax.  512 threads, p-tile 16.
// grid (256 nq, 8 pq) = 2048 blocks -> 3-4 blocks/CU co-resident.
// ---------------------------------------------------------------------------
__global__ __launch_bounds__(512, 4) void k_bd(
    const float* __restrict__ ER, const float* __restrict__ EI,
    const float* __restrict__ Vv, const float* __restrict__ cR, const float* __restrict__ cI,
    const float* __restrict__ ACm,
    float* __restrict__ AFF)
{
    // sVv [b][h][eo][k][4] (stride 20/eo) = 10240 f = 40960 B; logits reuse [0..639]
    __shared__ __align__(16) float uS[10240];
    const int t = threadIdx.x;
    const int w = t >> 6;            // 8 waves: b = w&3, sub = w>>2
    const int l = t & 63;
    const int b = w & 3, sub = w >> 2;
    const int eo = l & 15, pl = l >> 4;
    const int nq = blockIdx.x;
    const int pq = blockIdx.y;       // 0..7
    const int n = nq >> 7, q = nq & 127;
    const int P0 = pq * 16;
    // epilogue ownership (falls out of the butterfly): h = eo>>1, jj = eo&1
    const int hh = (eo >> 1) & 7, jjo = eo & 1;
    const int pown = P0 + sub * 8 + pl * 2 + jjo;

    // ---- early global loads (hoisted above barrier: overlap staging) ----
    float acm = ACm[(((hh * 2 + n) * 128 + q) * 4 + b) * 128 + pown];
    float crx = cR[(hh * 2 + n) * ROWS + q * 4 + b];
    float cix = cI[(hh * 2 + n) * ROWS + q * 4 + b];
    float4 A[2], Bv[2], C4[2], D4[2];
#pragma unroll
    for (int jj = 0; jj < 2; ++jj) {
        int p = P0 + sub * 8 + pl * 2 + jj;
        int qpo = (((n * 128 + q) * 128 + p) * 4 + b) * 64 + eo * 4;
        int pqo = (((n * 128 + p) * 128 + q) * 4 + b) * 64 + eo * 4;
        A[jj]  = *(const float4*)(ER + qpo);
        Bv[jj] = *(const float4*)(EI + qpo);
        C4[jj] = *(const float4*)(ER + pqo);
        D4[jj] = *(const float4*)(EI + pqo);
    }

    // ---- stage Vv: 2048 float4 over 512 threads, serves all 16 p ----
#pragma unroll
    for (int it = 0; it < 4; ++it) {
        int flat = t + 512 * it;                 // float4 units
        int e4 = flat & 15, k = (flat >> 4) & 3, h = (flat >> 6) & 7, bb = flat >> 9;
        float4 x = *(const float4*)&Vv[(unsigned)k * 524288u
                                       + ((h * 2 + n) * ROWS + q * 4 + bb) * 64u + e4 * 4];
        *(float4*)&uS[(bb * 8 + h) * 320 + e4 * 20 + k * 4] = x;
    }
    __syncthreads();

    float accr[8][2], acci[8][2];
#pragma unroll
    for (int h = 0; h < 8; ++h)
#pragma unroll
        for (int j = 0; j < 2; ++j) { accr[h][j] = 0.f; acci[h][j] = 0.f; }
#pragma unroll
    for (int h = 0; h < 8; ++h) {
        const float* vb = &uS[(b * 8 + h) * 320 + eo * 20];
        float4 v1 = *(const float4*)(vb);
        float4 v2 = *(const float4*)(vb + 4);
        float4 v3 = *(const float4*)(vb + 8);
        float4 v4 = *(const float4*)(vb + 12);
#pragma unroll
        for (int jj = 0; jj < 2; ++jj) {
            DOT4 (accr[h][jj], A[jj],  v1);
            NDOT4(accr[h][jj], Bv[jj], v2);
            NDOT4(accr[h][jj], C4[jj], v4);
            NDOT4(accr[h][jj], D4[jj], v3);
            DOT4 (acci[h][jj], A[jj],  v3);
            NDOT4(acci[h][jj], Bv[jj], v4);
            DOT4 (acci[h][jj], C4[jj], v2);
            DOT4 (acci[h][jj], D4[jj], v1);
        }
    }

    // ---- ownership-split butterfly over eo (masks 8,4,2,1) ----
    float r4[4][2], i4[4][2];
#pragma unroll
    for (int h2 = 0; h2 < 4; ++h2)
#pragma unroll
    for (int j = 0; j < 2; ++j) {
        float ra = accr[h2][j]     + __shfl_xor(accr[h2][j], 8);
        float rb = accr[h2 + 4][j] + __shfl_xor(accr[h2 + 4][j], 8);
        r4[h2][j] = (eo & 8) ? rb : ra;
        float ia = acci[h2][j]     + __shfl_xor(acci[h2][j], 8);
        float ib = acci[h2 + 4][j] + __shfl_xor(acci[h2 + 4][j], 8);
        i4[h2][j] = (eo & 8) ? ib : ia;
    }
    float r2a[2][2], i2a[2][2];
#pragma unroll
    for (int h1 = 0; h1 < 2; ++h1)
#pragma unroll
    for (int j = 0; j < 2; ++j) {
        float ra = r4[h1][j]     + __shfl_xor(r4[h1][j], 4);
        float rb = r4[h1 + 2][j] + __shfl_xor(r4[h1 + 2][j], 4);
        r2a[h1][j] = (eo & 4) ? rb : ra;
        float ia = i4[h1][j]     + __shfl_xor(i4[h1][j], 4);
        float ib = i4[h1 + 2][j] + __shfl_xor(i4[h1 + 2][j], 4);
        i2a[h1][j] = (eo & 4) ? ib : ia;
    }
    float r1a[2], i1a[2];
#pragma unroll
    for (int j = 0; j < 2; ++j) {
        float ra = r2a[0][j] + __shfl_xor(r2a[0][j], 2);
        float rb = r2a[1][j] + __shfl_xor(r2a[1][j], 2);
        r1a[j] = (eo & 2) ? rb : ra;
        float ia = i2a[0][j] + __shfl_xor(i2a[0][j], 2);
        float ib = i2a[1][j] + __shfl_xor(i2a[1][j], 2);
        i1a[j] = (eo & 2) ? ib : ia;
    }
    float ra0 = r1a[0] + __shfl_xor(r1a[0], 1);
    float rb0 = r1a[1] + __shfl_xor(r1a[1], 1);
    float rr  = (eo & 1) ? rb0 : ra0;
    float ia0 = i1a[0] + __shfl_xor(i1a[0], 1);
    float ib0 = i1a[1] + __shfl_xor(i1a[1], 1);
    float ii  = (eo & 1) ? ib0 : ia0;

    float bdr = rr + crx, bdi = ii + cix;
    float aff = acm + sqrtf(fmaf(bdr, bdr, bdi * bdi));
    float lg = aff * TEMPER;

    __syncthreads();                  // Vv region dead for all waves
    const int c = hh * 16 + sub * 8 + pl * 2 + jjo;   // 128 chains
    uS[c * 5 + b] = lg;
    __syncthreads();
    {
        float l0 = uS[c * 5 + 0], l1 = uS[c * 5 + 1];
        float l2 = uS[c * 5 + 2], l3 = uS[c * 5 + 3];
        float m = fmaxf(fmaxf(l0, l1), fmaxf(l2, l3));
        float s = __expf(l0 - m) + __expf(l1 - m) + __expf(l2 - m) + __expf(l3 - m);
        AFF[(unsigned)((nq * 4 + b) * 8 + hh) * 128 + pown] = __expf(lg - m) / s;
    }
}

// ---------------------------------------------------------------------------
// K6 (R1-proven): PV contraction. AFF layout [n][q][b][h][p].  grid 1024, block 256
// ---------------------------------------------------------------------------
__global__ __launch_bounds__(256) void k_pv(
    const float* __restrict__ AFF,
    const float* __restrict__ Vr, const float* __restrict__ Vi,
    float* __restrict__ out)
{
    __shared__ float sA[8 * 132];
    __shared__ float sRed[4 * 1092];
    const int t = threadIdx.x;
    const int nqb = blockIdx.x;
    const int b = nqb & 3, q = (nqb >> 2) & 127, n = nqb >> 9;
#pragma unroll
    for (int j = 0; j < 4; ++j) {
        int idx = t + 256 * j;
        sA[(idx >> 7) * 132 + (idx & 127)] = AFF[(unsigned)nqb * 1024u + idx];
    }
    __syncthreads();
    const int d = t & 63, pp = t >> 6;
    const float* vr = Vr + (n * 512 + b) * 64 + d;
    const float* vi = Vi + (n * 512 + b) * 64 + d;
    float oR[8], oI[8];
#pragma unroll
    for (int h = 0; h < 8; ++h) { oR[h] = 0.f; oI[h] = 0.f; }
    for (int pz = 0; pz < 32; ++pz) {
        int p = pp * 32 + pz;
        float xr = vr[p * 256];
        float xi = vi[p * 256];
#pragma unroll
        for (int h = 0; h < 8; ++h) {
            float a = sA[h * 132 + p];
            oR[h] = fmaf(a, xr, oR[h]);
            oI[h] = fmaf(a, xi, oI[h]);
        }
    }
    float* wb = sRed + pp * 1092;
#pragma unroll
    for (int s = 0; s < 16; ++s) {
        int h = s >> 1;
        wb[d * 17 + s] = (s & 1) ? oI[h] : oR[h];
    }
    __syncthreads();
    const int d2 = t & 63, g = t >> 6;
#pragma unroll
    for (int k = 0; k < 4; ++k) {
        int s = g * 4 + k;
        float v = sRed[0 * 1092 + d2 * 17 + s] + sRed[1 * 1092 + d2 * 17 + s]
                + sRed[2 * 1092 + d2 * 17 + s] + sRed[3 * 1092 + d2 * 17 + s];
        int h = s >> 1, ri = s & 1;
        out[(unsigned)ri * 524288u + ((n * 128 + q) * 4 + b) * 512u + h * 64 + d2] = v;
    }
}

// ---------------------------------------------------------------------------
extern "C" void kernel_launch(void* const* d_in, const int* in_sizes, int n_in,
                              void* d_out, int out_size, void* d_ws, size_t ws_size,
                              hipStream_t stream) {
    (void)in_sizes; (void)n_in; (void)out_size; (void)ws_size;
    const float* q_r  = (const float*)d_in[0];
    const float* q_i  = (const float*)d_in[1];
    const float* k_r  = (const float*)d_in[2];
    const float* k_i  = (const float*)d_in[3];
    const float* v_r  = (const float*)d_in[4];
    const float* v_i  = (const float*)d_in[5];
    const float* e_r  = (const float*)d_in[6];
    const float* e_i  = (const float*)d_in[7];
    const float* WKr_w  = (const float*)d_in[8];
    const float* WKi_w  = (const float*)d_in[10];
    const float* WKRr_w = (const float*)d_in[12];
    const float* WKRr_b = (const float*)d_in[13];
    const float* WKRi_w = (const float*)d_in[14];
    const float* WKRi_b = (const float*)d_in[15];
    const float* WQr_w  = (const float*)d_in[16];
    const float* WQi_w  = (const float*)d_in[18];
    const float* ww_r_g  = (const float*)d_in[20];
    const float* ww_r_bt = (const float*)d_in[21];
    const float* ww_i_g  = (const float*)d_in[22];
    const float* ww_i_bt = (const float*)d_in[23];
    const float* wr_r_g  = (const float*)d_in[24];
    const float* wr_r_bt = (const float*)d_in[25];
    const float* wr_i_g  = (const float*)d_in[26];
    const float* wr_i_bt = (const float*)d_in[27];
    float* ws  = (float*)d_ws;
    float* out = (float*)d_out;

    k_proj<<<dim3(16, 16, 2), 256, 0, stream>>>(q_r, q_i, k_r, k_i,
                                                WQr_w, WQi_w, WKr_w, WKi_w,
                                                ws, ws + PART_);
    k_mid<<<dim3(1536), 256, 0, stream>>>(ws + WQ_R, ws + WQ_I, ws + WK_R, ws + WK_I,
                                          ws + PART_,
                                          WKRr_w, WKRi_w, WKRr_b, WKRi_b,
                                          wr_r_g, wr_r_bt, wr_i_g, wr_i_bt,
                                          ww_r_g, ww_r_bt, ww_i_g, ww_i_bt,
                                          ws + VV_, ws + C_R_, ws + C_I_, ws + ACM_);
    k_bd<<<dim3(256, 8), 512, 0, stream>>>(e_r, e_i, ws + VV_, ws + C_R_, ws + C_I_,
                                           ws + ACM_, ws + AFF_);
    k_pv<<<1024, 256, 0, stream>>>(ws + AFF_, v_r, v_i, out);
}

// Round 6
// 211.673 us; speedup vs baseline: 1.2101x; 1.0237x over previous
//
#include <hip/hip_runtime.h>
#include <math.h>

// Problem constants
#define NH 8
#define DDIM 64
#define NN 2
#define QQ 128
#define PPDIM 128
#define BBD 4
#define ROWS 512           // Q*B == P*B
#define EPSN 1e-5f
#define TEMPER 30.0f

// Workspace layout (float offsets)
#define WQ_R 0u            // [H][N][512][64] rows = q*4+b
#define WQ_I 524288u
#define WK_R 1048576u      // rows = p*4+b
#define WK_I 1572864u
#define VV_  2105344u      // 4 x [H][N][512][64]  (v1,v2,v3,v4)
#define C_R_ 4202496u      // [H][N][512]
#define C_I_ 4210688u
#define ACM_ 4218880u      // [H][N][Q][B][P]  magnitude only
#define AFF_ 6316032u      // [N][Q][B][H][P]
// stats partials live in AFF region (dead until k_bd): [grp 64][sv 2][rt 16][d 64]
#define PART_ AFF_

#define DOT4(acc, s, v)  { acc = fmaf((s).x,(v).x,acc); acc = fmaf((s).y,(v).y,acc); acc = fmaf((s).z,(v).z,acc); acc = fmaf((s).w,(v).w,acc); }
#define NDOT4(acc, s, v) { acc = fmaf(-(s).x,(v).x,acc); acc = fmaf(-(s).y,(v).y,acc); acc = fmaf(-(s).z,(v).z,acc); acc = fmaf(-(s).w,(v).w,acc); }

// ---------------------------------------------------------------------------
// K1 v3: complex projection (pre-norm) + fused InstanceNorm partial stats.
// dout range split in half per block: LDS 18.4KB, grid (32 = rt16 + 16*dh,
// 16 hn, 2 z) = 1024 blocks -> 4 blocks/CU = 16 waves/CU.
// W staged with COALESCED global reads (lane = e) into [e][36] layout
// (conflict-free b128 reads, 16B-aligned: 144 bytes/row).
// Per-thread: 1 row x 4 douts; per-u: 2 b128 LDS (24cy) vs 16 fma (32cy).
// ---------------------------------------------------------------------------
__global__ __launch_bounds__(256) void k_proj(
    const float* __restrict__ qR, const float* __restrict__ qI,
    const float* __restrict__ kR, const float* __restrict__ kI,
    const float* __restrict__ WQr, const float* __restrict__ WQi,
    const float* __restrict__ WKr, const float* __restrict__ WKi,
    float* __restrict__ ws, float* __restrict__ part)
{
    __shared__ __align__(16) float sW0[64 * 36];   // [e][dout32 + pad]
    __shared__ __align__(16) float sW1[64 * 36];
    const int t  = threadIdx.x;
    const int bx = blockIdx.x;
    const int rt = bx & 15, dh = bx >> 4;          // dh 0/1: dout half
    const int hn = blockIdx.y;
    const int z  = blockIdx.z;
    const int h = hn >> 1, n = hn & 1;
    const float* inR = z ? kR : qR;
    const float* inI = z ? kI : qI;
    const float* wr0 = (z ? WKr : WQr) + h * 4096;
    const float* wi0 = (z ? WKi : WQi) + h * 4096;
    float* outR = ws + (z ? WK_R : WQ_R);
    float* outI = ws + (z ? WK_I : WQ_I);
    // stage W half, transposed; global reads coalesced (lane = e)
#pragma unroll
    for (int j = 0; j < 8; ++j) {
        int flat = t + 256 * j;          // 0..2047
        int e = flat & 63, dout = flat >> 6;   // dout 0..31
        sW0[e * 36 + dout] = wr0[(dh * 32 + dout) * 64 + e];
        sW1[e * 36 + dout] = wi0[(dh * 32 + dout) * 64 + e];
    }
    __syncthreads();
    const int row = t & 31, dq = t >> 5;   // dq 0..7 -> douts dq*4..+3 (in half)
    const int rowg = rt * 32 + row;
    const float4* xr4 = (const float4*)(inR + (n * ROWS + rowg) * 64);
    const float4* xi4 = (const float4*)(inI + (n * ROWS + rowg) * 64);
    float ar[4], ai[4];
#pragma unroll
    for (int j = 0; j < 4; ++j) { ar[j] = 0.f; ai[j] = 0.f; }
    for (int ec = 0; ec < 16; ++ec) {
        float4 xrv = xr4[ec], xiv = xi4[ec];
        float xrs[4] = {xrv.x, xrv.y, xrv.z, xrv.w};
        float xis[4] = {xiv.x, xiv.y, xiv.z, xiv.w};
#pragma unroll
        for (int u = 0; u < 4; ++u) {
            int e = ec * 4 + u;
            float4 wr = *(const float4*)&sW0[e * 36 + dq * 4];
            float4 wi = *(const float4*)&sW1[e * 36 + dq * 4];
            float xr = xrs[u], xi = xis[u];
            ar[0] = fmaf(xr, wr.x, fmaf(-xi, wi.x, ar[0]));
            ar[1] = fmaf(xr, wr.y, fmaf(-xi, wi.y, ar[1]));
            ar[2] = fmaf(xr, wr.z, fmaf(-xi, wi.z, ar[2]));
            ar[3] = fmaf(xr, wr.w, fmaf(-xi, wi.w, ar[3]));
            ai[0] = fmaf(xr, wi.x, fmaf( xi, wr.x, ai[0]));
            ai[1] = fmaf(xr, wi.y, fmaf( xi, wr.y, ai[1]));
            ai[2] = fmaf(xr, wi.z, fmaf( xi, wr.z, ai[2]));
            ai[3] = fmaf(xr, wi.w, fmaf( xi, wr.w, ai[3]));
        }
    }
    float* oR = outR + ((unsigned)hn * ROWS + rowg) * 64 + dh * 32 + dq * 4;
    float* oI = outI + ((unsigned)hn * ROWS + rowg) * 64 + dh * 32 + dq * 4;
    *(float4*)oR = make_float4(ar[0], ar[1], ar[2], ar[3]);
    *(float4*)oI = make_float4(ai[0], ai[1], ai[2], ai[3]);
    // ---- fused stats partials: sum over this block's 32 rows ----
    float s_r[4], q_r8[4], s_i[4], q_i8[4];
#pragma unroll
    for (int i = 0; i < 4; ++i) {
        s_r[i] = ar[i]; q_r8[i] = ar[i] * ar[i];
        s_i[i] = ai[i]; q_i8[i] = ai[i] * ai[i];
    }
#pragma unroll
    for (int m = 1; m <= 16; m <<= 1) {
#pragma unroll
        for (int i = 0; i < 4; ++i) {
            s_r[i]  += __shfl_xor(s_r[i],  m);
            q_r8[i] += __shfl_xor(q_r8[i], m);
            s_i[i]  += __shfl_xor(s_i[i],  m);
            q_i8[i] += __shfl_xor(q_i8[i], m);
        }
    }
    if ((t & 31) == 0) {
        const int gr = (z * 2) * 16 + hn;        // out_r tensor group
        const int gi = (z * 2 + 1) * 16 + hn;    // out_i tensor group
#pragma unroll
        for (int i = 0; i < 4; ++i) {
            int d = dh * 32 + dq * 4 + i;
            part[(unsigned)gr * 2048u + rt * 64 + d]          = s_r[i];
            part[(unsigned)gr * 2048u + 1024 + rt * 64 + d]   = q_r8[i];
            part[(unsigned)gi * 2048u + rt * 64 + d]          = s_i[i];
            part[(unsigned)gi * 2048u + 1024 + rt * 64 + d]   = q_i8[i];
        }
    }
}

// ---------------------------------------------------------------------------
// K2 (fused): role A = v-vectors + bias dots (blocks 0..511, unchanged)
//             role B = AC magnitude, 2p x 4q per thread, Karatsuba with
//             on-the-fly sum vectors (blocks 512..1023; 32-q tiles)
// ---------------------------------------------------------------------------
__global__ __launch_bounds__(256) void k_mid(
    const float* __restrict__ wqr, const float* __restrict__ wqi,
    const float* __restrict__ wkr, const float* __restrict__ wki,
    const float* __restrict__ part,
    const float* __restrict__ Ar,  const float* __restrict__ Ai,
    const float* __restrict__ Abr, const float* __restrict__ Abi,
    const float* __restrict__ grv, const float* __restrict__ btrv,
    const float* __restrict__ giv, const float* __restrict__ btiv,
    const float* __restrict__ gwr, const float* __restrict__ btwr,
    const float* __restrict__ gwi, const float* __restrict__ btwi,
    float* __restrict__ Vout, float* __restrict__ cR, float* __restrict__ cI,
    float* __restrict__ ACm)
{
    __shared__ __align__(16) float smem[13440];   // 53.76 KB -> 3 blocks/CU
    const int t = threadIdx.x;
    if (blockIdx.x < 512) {
        // =========================== role A: vvec ===========================
        float* sW0 = smem;            // [64][32]
        float* sW1 = smem + 2048;
        float* sX0 = smem + 4096;     // [64][32] swizzled
        float* sX1 = smem + 6144;
        float* sMu = smem + 8192;     // [2][64]
        float* sRs = smem + 8320;     // [2][64]
        const int b1 = blockIdx.x;
        const int rt = b1 & 15, eh = (b1 >> 4) & 1, hn = b1 >> 5, h = hn >> 1;
        if (t < 128) {
            int g = t >> 6, d = t & 63;
            int grp = (g ? 16 : 0) + hn;
            const float* ps = part + (unsigned)grp * 2048u + d;
            float s = 0.f, qq = 0.f;
#pragma unroll
            for (int r2 = 0; r2 < 16; ++r2) {
                s  += ps[r2 * 64];
                qq += ps[1024 + r2 * 64];
            }
            float m = s * (1.f / 512.f);
            float var = qq * (1.f / 512.f) - m * m;
            sMu[g * 64 + d] = m;
            sRs[g * 64 + d] = rsqrtf(var + EPSN);
        }
        const float* a0 = Ar + h * 4096;
        const float* a1 = Ai + h * 4096;
#pragma unroll
        for (int j = 0; j < 8; ++j) {
            int flat = t + 256 * j;
            int c = flat & 31, r = flat >> 5;
            sW0[r * 32 + c] = a0[r * 64 + eh * 32 + c];
            sW1[r * 32 + c] = a1[r * 64 + eh * 32 + c];
        }
        __syncthreads();
        {
            const int d = t & 63;
            const float m0 = sMu[d],      r0 = sRs[d],      g0 = grv[h * 64 + d], b0 = btrv[h * 64 + d];
            const float m1 = sMu[64 + d], r1 = sRs[64 + d], g1 = giv[h * 64 + d], bt1 = btiv[h * 64 + d];
#pragma unroll
            for (int j = 0; j < 8; ++j) {
                int row = (t >> 6) + 4 * j;  // 0..31
                int gidx = (hn * ROWS + rt * 32 + row) * 64 + d;
                float xr = wqr[gidx], xi = wqi[gidx];
                sX0[d * 32 + ((row + d) & 31)] = (xr - m0) * r0 * g0 + b0;
                sX1[d * 32 + ((row + d) & 31)] = (xi - m1) * r1 * g1 + bt1;
            }
        }
        __syncthreads();
        const int eq = t & 7, row = t >> 3;   // eq fast -> coalesced stores
        float v[4][4];
#pragma unroll
        for (int k = 0; k < 4; ++k)
#pragma unroll
            for (int j = 0; j < 4; ++j) v[k][j] = 0.f;
        for (int d = 0; d < 64; ++d) {
            float xr = sX0[d * 32 + ((row + d) & 31)];
            float xi = sX1[d * 32 + ((row + d) & 31)];
            float4 wr = *(const float4*)&sW0[d * 32 + eq * 4];
            float4 wi = *(const float4*)&sW1[d * 32 + eq * 4];
            v[0][0] = fmaf(xr, wr.x, v[0][0]); v[0][1] = fmaf(xr, wr.y, v[0][1]);
            v[0][2] = fmaf(xr, wr.z, v[0][2]); v[0][3] = fmaf(xr, wr.w, v[0][3]);
            v[1][0] = fmaf(xr, wi.x, v[1][0]); v[1][1] = fmaf(xr, wi.y, v[1][1]);
            v[1][2] = fmaf(xr, wi.z, v[1][2]); v[1][3] = fmaf(xr, wi.w, v[1][3]);
            v[2][0] = fmaf(xi, wr.x, v[2][0]); v[2][1] = fmaf(xi, wr.y, v[2][1]);
            v[2][2] = fmaf(xi, wr.z, v[2][2]); v[2][3] = fmaf(xi, wr.w, v[2][3]);
            v[3][0] = fmaf(xi, wi.x, v[3][0]); v[3][1] = fmaf(xi, wi.y, v[3][1]);
            v[3][2] = fmaf(xi, wi.z, v[3][2]); v[3][3] = fmaf(xi, wi.w, v[3][3]);
        }
        const int rowg = rt * 32 + row;
#pragma unroll
        for (int k = 0; k < 4; ++k) {
            float* o = Vout + (unsigned)k * 524288u + (hn * ROWS + rowg) * 64 + eh * 32 + eq * 4;
            *(float4*)o = make_float4(v[k][0], v[k][1], v[k][2], v[k][3]);
        }
        if (eh == 0 && t < 32) {
            const int rw = t;
            float cr = 0.f, ci = 0.f;
            for (int d = 0; d < 64; ++d) {
                float br = Abr[h * 64 + d], bi = Abi[h * 64 + d];
                float bm = br - bi, bp = br + bi;
                float xr = sX0[d * 32 + ((rw + d) & 31)];
                float xi = sX1[d * 32 + ((rw + d) & 31)];
                cr = fmaf(bm, xr, fmaf(-bp, xi, cr));
                ci = fmaf(bm, xi, fmaf( bp, xr, ci));
            }
            cR[hn * ROWS + rt * 32 + rw] = cr;
            cI[hn * ROWS + rt * 32 + rw] = ci;
        }
    } else {
        // ============================ role B: ac ============================
        // grid decode: 512 blocks = qt(4, 32q) x ph(2) x hn(16) x b(4)
        float* sK0 = smem;              // [64 p][65]
        float* sK1 = smem + 4160;
        float* sQ0 = smem + 8320;       // [64 e][36]  (32 q + pad)
        float* sQ1 = smem + 10624;
        float* sMu = smem + 12928;      // [4][64]
        float* sRs = smem + 13184;      // [4][64]
        const int idx = blockIdx.x - 512;
        const int qt = idx & 3, ph = (idx >> 2) & 1, hn = (idx >> 3) & 15;
        const int b = idx >> 7, h = hn >> 1;
        {
            int g = t >> 6, d = t & 63;
            int grp = g * 16 + hn;
            const float* ps = part + (unsigned)grp * 2048u + d;
            float s = 0.f, qq = 0.f;
#pragma unroll
            for (int r2 = 0; r2 < 16; ++r2) {
                s  += ps[r2 * 64];
                qq += ps[1024 + r2 * 64];
            }
            float m = s * (1.f / 512.f);
            float var = qq * (1.f / 512.f) - m * m;
            sMu[g * 64 + d] = m;
            sRs[g * 64 + d] = rsqrtf(var + EPSN);
        }
        __syncthreads();
        // stage K: 64 p x 64 e, normalized, [p][e] with pad 65
#pragma unroll
        for (int j = 0; j < 4; ++j) {
            int flat4 = t + 256 * j;
            int word = flat4 * 4;
            int pp = word >> 6, ee = word & 63;
            int gidx = (hn * ROWS + (ph * 64 + pp) * 4 + b) * 64 + ee;
            float4 kr = *(const float4*)&wkr[gidx];
            float4 ki = *(const float4*)&wki[gidx];
            float4 m2 = *(const float4*)&sMu[128 + ee]; float4 r2 = *(const float4*)&sRs[128 + ee];
            float4 m3 = *(const float4*)&sMu[192 + ee]; float4 r3 = *(const float4*)&sRs[192 + ee];
            sK0[pp * 65 + ee + 0] = (kr.x - m2.x) * r2.x; sK0[pp * 65 + ee + 1] = (kr.y - m2.y) * r2.y;
            sK0[pp * 65 + ee + 2] = (kr.z - m2.z) * r2.z; sK0[pp * 65 + ee + 3] = (kr.w - m2.w) * r2.w;
            sK1[pp * 65 + ee + 0] = (ki.x - m3.x) * r3.x; sK1[pp * 65 + ee + 1] = (ki.y - m3.y) * r3.y;
            sK1[pp * 65 + ee + 2] = (ki.z - m3.z) * r3.z; sK1[pp * 65 + ee + 3] = (ki.w - m3.w) * r3.w;
        }
        // stage Q: 32 q x 64 d, normalized+affine, transposed [d][q] pad 36
#pragma unroll
        for (int j = 0; j < 2; ++j) {
            int flat4 = t + 256 * j;          // 0..511
            int qq = flat4 >> 4;              // 0..31
            int dd = (flat4 & 15) * 4;
            int gidx = (hn * ROWS + (qt * 32 + qq) * 4 + b) * 64 + dd;
            float4 xr = *(const float4*)&wqr[gidx];
            float4 xi = *(const float4*)&wqi[gidx];
            float4 m0 = *(const float4*)&sMu[dd];      float4 r0 = *(const float4*)&sRs[dd];
            float4 m1 = *(const float4*)&sMu[64 + dd]; float4 r1 = *(const float4*)&sRs[64 + dd];
            float4 g0 = *(const float4*)&gwr[h * 64 + dd]; float4 b0 = *(const float4*)&btwr[h * 64 + dd];
            float4 g1 = *(const float4*)&gwi[h * 64 + dd]; float4 b1 = *(const float4*)&btwi[h * 64 + dd];
            sQ0[(dd + 0) * 36 + qq] = fmaf((xr.x - m0.x) * r0.x, g0.x, b0.x);
            sQ0[(dd + 1) * 36 + qq] = fmaf((xr.y - m0.y) * r0.y, g0.y, b0.y);
            sQ0[(dd + 2) * 36 + qq] = fmaf((xr.z - m0.z) * r0.z, g0.z, b0.z);
            sQ0[(dd + 3) * 36 + qq] = fmaf((xr.w - m0.w) * r0.w, g0.w, b0.w);
            sQ1[(dd + 0) * 36 + qq] = fmaf((xi.x - m1.x) * r1.x, g1.x, b1.x);
            sQ1[(dd + 1) * 36 + qq] = fmaf((xi.y - m1.y) * r1.y, g1.y, b1.y);
            sQ1[(dd + 2) * 36 + qq] = fmaf((xi.z - m1.z) * r1.z, g1.z, b1.z);
            sQ1[(dd + 3) * 36 + qq] = fmaf((xi.w - m1.w) * r1.w, g1.w, b1.w);
        }
        __syncthreads();
        const int p2 = t & 31, qs = t >> 5;   // p in {p2, p2+32}; q = qt*32+qs*4+j
        float p1a[2][4], p2a[2][4], p3a[2][4];
#pragma unroll
        for (int pp = 0; pp < 2; ++pp)
#pragma unroll
            for (int j = 0; j < 4; ++j) { p1a[pp][j] = 0.f; p2a[pp][j] = 0.f; p3a[pp][j] = 0.f; }
        for (int e = 0; e < 64; ++e) {
            float kr0 = sK0[p2 * 65 + e],        ki0 = sK1[p2 * 65 + e];
            float kr1 = sK0[(p2 + 32) * 65 + e], ki1 = sK1[(p2 + 32) * 65 + e];
            float ks0 = kr0 + ki0, ks1 = kr1 + ki1;
            float4 qr = *(const float4*)&sQ0[e * 36 + qs * 4];
            float4 qi = *(const float4*)&sQ1[e * 36 + qs * 4];
            float4 qsv = make_float4(qr.x + qi.x, qr.y + qi.y, qr.z + qi.z, qr.w + qi.w);
            p1a[0][0] = fmaf(kr0, qr.x, p1a[0][0]); p1a[0][1] = fmaf(kr0, qr.y, p1a[0][1]);
            p1a[0][2] = fmaf(kr0, qr.z, p1a[0][2]); p1a[0][3] = fmaf(kr0, qr.w, p1a[0][3]);
            p2a[0][0] = fmaf(ki0, qi.x, p2a[0][0]); p2a[0][1] = fmaf(ki0, qi.y, p2a[0][1]);
            p2a[0][2] = fmaf(ki0, qi.z, p2a[0][2]); p2a[0][3] = fmaf(ki0, qi.w, p2a[0][3]);
            p3a[0][0] = fmaf(ks0, qsv.x, p3a[0][0]); p3a[0][1] = fmaf(ks0, qsv.y, p3a[0][1]);
            p3a[0][2] = fmaf(ks0, qsv.z, p3a[0][2]); p3a[0][3] = fmaf(ks0, qsv.w, p3a[0][3]);
            p1a[1][0] = fmaf(kr1, qr.x, p1a[1][0]); p1a[1][1] = fmaf(kr1, qr.y, p1a[1][1]);
            p1a[1][2] = fmaf(kr1, qr.z, p1a[1][2]); p1a[1][3] = fmaf(kr1, qr.w, p1a[1][3]);
            p2a[1][0] = fmaf(ki1, qi.x, p2a[1][0]); p2a[1][1] = fmaf(ki1, qi.y, p2a[1][1]);
            p2a[1][2] = fmaf(ki1, qi.z, p2a[1][2]); p2a[1][3] = fmaf(ki1, qi.w, p2a[1][3]);
            p3a[1][0] = fmaf(ks1, qsv.x, p3a[1][0]); p3a[1][1] = fmaf(ks1, qsv.y, p3a[1][1]);
            p3a[1][2] = fmaf(ks1, qsv.z, p3a[1][2]); p3a[1][3] = fmaf(ks1, qsv.w, p3a[1][3]);
        }
#pragma unroll
        for (int pp = 0; pp < 2; ++pp)
#pragma unroll
        for (int j = 0; j < 4; ++j) {
            float acr = p1a[pp][j] - p2a[pp][j];
            float aci = p3a[pp][j] - p1a[pp][j] - p2a[pp][j];
            int qv = qt * 32 + qs * 4 + j;
            int oidx = ((hn * 128 + qv) * 4 + b) * 128 + ph * 64 + pp * 32 + p2;
            ACm[oidx] = sqrtf(fmaf(acr, acr, aci * aci));
        }
    }
}

// ---------------------------------------------------------------------------
// K5 (R1-proven): fused BD + AC + affinity + softmax.  512 threads, p-tile 16.
// grid (256 nq, 8 pq) = 2048 blocks.
// ---------------------------------------------------------------------------
__global__ __launch_bounds__(512, 4) void k_bd(
    const float* __restrict__ ER, const float* __restrict__ EI,
    const float* __restrict__ Vv, const float* __restrict__ cR, const float* __restrict__ cI,
    const float* __restrict__ ACm,
    float* __restrict__ AFF)
{
    __shared__ __align__(16) float uS[10240];
    const int t = threadIdx.x;
    const int w = t >> 6;            // 8 waves: b = w&3, sub = w>>2
    const int l = t & 63;
    const int b = w & 3, sub = w >> 2;
    const int eo = l & 15, pl = l >> 4;
    const int nq = blockIdx.x;
    const int pq = blockIdx.y;       // 0..7
    const int n = nq >> 7, q = nq & 127;
    const int P0 = pq * 16;
    const int hh = (eo >> 1) & 7, jjo = eo & 1;
    const int pown = P0 + sub * 8 + pl * 2 + jjo;

    float acm = ACm[(((hh * 2 + n) * 128 + q) * 4 + b) * 128 + pown];
    float crx = cR[(hh * 2 + n) * ROWS + q * 4 + b];
    float cix = cI[(hh * 2 + n) * ROWS + q * 4 + b];
    float4 A[2], Bv[2], C4[2], D4[2];
#pragma unroll
    for (int jj = 0; jj < 2; ++jj) {
        int p = P0 + sub * 8 + pl * 2 + jj;
        int qpo = (((n * 128 + q) * 128 + p) * 4 + b) * 64 + eo * 4;
        int pqo = (((n * 128 + p) * 128 + q) * 4 + b) * 64 + eo * 4;
        A[jj]  = *(const float4*)(ER + qpo);
        Bv[jj] = *(const float4*)(EI + qpo);
        C4[jj] = *(const float4*)(ER + pqo);
        D4[jj] = *(const float4*)(EI + pqo);
    }

#pragma unroll
    for (int it = 0; it < 4; ++it) {
        int flat = t + 512 * it;
        int e4 = flat & 15, k = (flat >> 4) & 3, h = (flat >> 6) & 7, bb = flat >> 9;
        float4 x = *(const float4*)&Vv[(unsigned)k * 524288u
                                       + ((h * 2 + n) * ROWS + q * 4 + bb) * 64u + e4 * 4];
        *(float4*)&uS[(bb * 8 + h) * 320 + e4 * 20 + k * 4] = x;
    }
    __syncthreads();

    float accr[8][2], acci[8][2];
#pragma unroll
    for (int h = 0; h < 8; ++h)
#pragma unroll
        for (int j = 0; j < 2; ++j) { accr[h][j] = 0.f; acci[h][j] = 0.f; }
#pragma unroll
    for (int h = 0; h < 8; ++h) {
        const float* vb = &uS[(b * 8 + h) * 320 + eo * 20];
        float4 v1 = *(const float4*)(vb);
        float4 v2 = *(const float4*)(vb + 4);
        float4 v3 = *(const float4*)(vb + 8);
        float4 v4 = *(const float4*)(vb + 12);
#pragma unroll
        for (int jj = 0; jj < 2; ++jj) {
            DOT4 (accr[h][jj], A[jj],  v1);
            NDOT4(accr[h][jj], Bv[jj], v2);
            NDOT4(accr[h][jj], C4[jj], v4);
            NDOT4(accr[h][jj], D4[jj], v3);
            DOT4 (acci[h][jj], A[jj],  v3);
            NDOT4(acci[h][jj], Bv[jj], v4);
            DOT4 (acci[h][jj], C4[jj], v2);
            DOT4 (acci[h][jj], D4[jj], v1);
        }
    }

    float r4[4][2], i4[4][2];
#pragma unroll
    for (int h2 = 0; h2 < 4; ++h2)
#pragma unroll
    for (int j = 0; j < 2; ++j) {
        float ra = accr[h2][j]     + __shfl_xor(accr[h2][j], 8);
        float rb = accr[h2 + 4][j] + __shfl_xor(accr[h2 + 4][j], 8);
        r4[h2][j] = (eo & 8) ? rb : ra;
        float ia = acci[h2][j]     + __shfl_xor(acci[h2][j], 8);
        float ib = acci[h2 + 4][j] + __shfl_xor(acci[h2 + 4][j], 8);
        i4[h2][j] = (eo & 8) ? ib : ia;
    }
    float r2a[2][2], i2a[2][2];
#pragma unroll
    for (int h1 = 0; h1 < 2; ++h1)
#pragma unroll
    for (int j = 0; j < 2; ++j) {
        float ra = r4[h1][j]     + __shfl_xor(r4[h1][j], 4);
        float rb = r4[h1 + 2][j] + __shfl_xor(r4[h1 + 2][j], 4);
        r2a[h1][j] = (eo & 4) ? rb : ra;
        float ia = i4[h1][j]     + __shfl_xor(i4[h1][j], 4);
        float ib = i4[h1 + 2][j] + __shfl_xor(i4[h1 + 2][j], 4);
        i2a[h1][j] = (eo & 4) ? ib : ia;
    }
    float r1a[2], i1a[2];
#pragma unroll
    for (int j = 0; j < 2; ++j) {
        float ra = r2a[0][j] + __shfl_xor(r2a[0][j], 2);
        float rb = r2a[1][j] + __shfl_xor(r2a[1][j], 2);
        r1a[j] = (eo & 2) ? rb : ra;
        float ia = i2a[0][j] + __shfl_xor(i2a[0][j], 2);
        float ib = i2a[1][j] + __shfl_xor(i2a[1][j], 2);
        i1a[j] = (eo & 2) ? ib : ia;
    }
    float ra0 = r1a[0] + __shfl_xor(r1a[0], 1);
    float rb0 = r1a[1] + __shfl_xor(r1a[1], 1);
    float rr  = (eo & 1) ? rb0 : ra0;
    float ia0 = i1a[0] + __shfl_xor(i1a[0], 1);
    float ib0 = i1a[1] + __shfl_xor(i1a[1], 1);
    float ii  = (eo & 1) ? ib0 : ia0;

    float bdr = rr + crx, bdi = ii + cix;
    float aff = acm + sqrtf(fmaf(bdr, bdr, bdi * bdi));
    float lg = aff * TEMPER;

    __syncthreads();
    const int c = hh * 16 + sub * 8 + pl * 2 + jjo;
    uS[c * 5 + b] = lg;
    __syncthreads();
    {
        float l0 = uS[c * 5 + 0], l1 = uS[c * 5 + 1];
        float l2 = uS[c * 5 + 2], l3 = uS[c * 5 + 3];
        float m = fmaxf(fmaxf(l0, l1), fmaxf(l2, l3));
        float s = __expf(l0 - m) + __expf(l1 - m) + __expf(l2 - m) + __expf(l3 - m);
        AFF[(unsigned)((nq * 4 + b) * 8 + hh) * 128 + pown] = __expf(lg - m) / s;
    }
}

// ---------------------------------------------------------------------------
// K6 (R1-proven): PV contraction. AFF layout [n][q][b][h][p].  grid 1024, block 256
// ---------------------------------------------------------------------------
__global__ __launch_bounds__(256) void k_pv(
    const float* __restrict__ AFF,
    const float* __restrict__ Vr, const float* __restrict__ Vi,
    float* __restrict__ out)
{
    __shared__ float sA[8 * 132];
    __shared__ float sRed[4 * 1092];
    const int t = threadIdx.x;
    const int nqb = blockIdx.x;
    const int b = nqb & 3, q = (nqb >> 2) & 127, n = nqb >> 9;
#pragma unroll
    for (int j = 0; j < 4; ++j) {
        int idx = t + 256 * j;
        sA[(idx >> 7) * 132 + (idx & 127)] = AFF[(unsigned)nqb * 1024u + idx];
    }
    __syncthreads();
    const int d = t & 63, pp = t >> 6;
    const float* vr = Vr + (n * 512 + b) * 64 + d;
    const float* vi = Vi + (n * 512 + b) * 64 + d;
    float oR[8], oI[8];
#pragma unroll
    for (int h = 0; h < 8; ++h) { oR[h] = 0.f; oI[h] = 0.f; }
    for (int pz = 0; pz < 32; ++pz) {
        int p = pp * 32 + pz;
        float xr = vr[p * 256];
        float xi = vi[p * 256];
#pragma unroll
        for (int h = 0; h < 8; ++h) {
            float a = sA[h * 132 + p];
            oR[h] = fmaf(a, xr, oR[h]);
            oI[h] = fmaf(a, xi, oI[h]);
        }
    }
    float* wb = sRed + pp * 1092;
#pragma unroll
    for (int s = 0; s < 16; ++s) {
        int h = s >> 1;
        wb[d * 17 + s] = (s & 1) ? oI[h] : oR[h];
    }
    __syncthreads();
    const int d2 = t & 63, g = t >> 6;
#pragma unroll
    for (int k = 0; k < 4; ++k) {
        int s = g * 4 + k;
        float v = sRed[0 * 1092 + d2 * 17 + s] + sRed[1 * 1092 + d2 * 17 + s]
                + sRed[2 * 1092 + d2 * 17 + s] + sRed[3 * 1092 + d2 * 17 + s];
        int h = s >> 1, ri = s & 1;
        out[(unsigned)ri * 524288u + ((n * 128 + q) * 4 + b) * 512u + h * 64 + d2] = v;
    }
}

// ---------------------------------------------------------------------------
extern "C" void kernel_launch(void* const* d_in, const int* in_sizes, int n_in,
                              void* d_out, int out_size, void* d_ws, size_t ws_size,
                              hipStream_t stream) {
    (void)in_sizes; (void)n_in; (void)out_size; (void)ws_size;
    const float* q_r  = (const float*)d_in[0];
    const float* q_i  = (const float*)d_in[1];
    const float* k_r  = (const float*)d_in[2];
    const float* k_i  = (const float*)d_in[3];
    const float* v_r  = (const float*)d_in[4];
    const float* v_i  = (const float*)d_in[5];
    const float* e_r  = (const float*)d_in[6];
    const float* e_i  = (const float*)d_in[7];
    const float* WKr_w  = (const float*)d_in[8];
    const float* WKi_w  = (const float*)d_in[10];
    const float* WKRr_w = (const float*)d_in[12];
    const float* WKRr_b = (const float*)d_in[13];
    const float* WKRi_w = (const float*)d_in[14];
    const float* WKRi_b = (const float*)d_in[15];
    const float* WQr_w  = (const float*)d_in[16];
    const float* WQi_w  = (const float*)d_in[18];
    const float* ww_r_g  = (const float*)d_in[20];
    const float* ww_r_bt = (const float*)d_in[21];
    const float* ww_i_g  = (const float*)d_in[22];
    const float* ww_i_bt = (const float*)d_in[23];
    const float* wr_r_g  = (const float*)d_in[24];
    const float* wr_r_bt = (const float*)d_in[25];
    const float* wr_i_g  = (const float*)d_in[26];
    const float* wr_i_bt = (const float*)d_in[27];
    float* ws  = (float*)d_ws;
    float* out = (float*)d_out;

    k_proj<<<dim3(32, 16, 2), 256, 0, stream>>>(q_r, q_i, k_r, k_i,
                                                WQr_w, WQi_w, WKr_w, WKi_w,
                                                ws, ws + PART_);
    k_mid<<<dim3(1024), 256, 0, stream>>>(ws + WQ_R, ws + WQ_I, ws + WK_R, ws + WK_I,
                                          ws + PART_,
                                          WKRr_w, WKRi_w, WKRr_b, WKRi_b,
                                          wr_r_g, wr_r_bt, wr_i_g, wr_i_bt,
                                          ww_r_g, ww_r_bt, ww_i_g, ww_i_bt,
                                          ws + VV_, ws + C_R_, ws + C_I_, ws + ACM_);
    k_bd<<<dim3(256, 8), 512, 0, stream>>>(e_r, e_i, ws + VV_, ws + C_R_, ws + C_I_,
                                           ws + ACM_, ws + AFF_);
    k_pv<<<1024, 256, 0, stream>>>(ws + AFF_, v_r, v_i, out);
}